// Round 12
// baseline (8764.304 us; speedup 1.0000x reference)
//
#include <hip/hip_runtime.h>
#include <hip/hip_bf16.h>

#define TT 512
#define BB 64
#define DD 1024
#define HH 1024
#define NG4 4096
#define NWG 128
#define SLOT 131072       // bf16 elems per h slot (4 blocks x 32768)
#define SLOTB 262144      // bytes per h slot

typedef short bf16x8 __attribute__((ext_vector_type(8)));
typedef float f32x4 __attribute__((ext_vector_type(4)));
typedef __hip_bfloat16 bf16;

static __device__ __forceinline__ unsigned short bfbits(float f) {
  bf16 h = __float2bfloat16(f);
  return *reinterpret_cast<unsigned short*>(&h);
}
static __device__ __forceinline__ float bf2f(unsigned short u) {
  bf16 h = *reinterpret_cast<bf16*>(&u);
  return __bfloat162float(h);
}
static __device__ __forceinline__ void st_agent4(void* p, unsigned v) {
  __hip_atomic_store((unsigned*)p, v, __ATOMIC_RELAXED, __HIP_MEMORY_SCOPE_AGENT);
}
// async global->LDS, 16B per lane; dest must be lane-linear (base + lane*16)
static __device__ __forceinline__ void gload_lds16(const bf16* g, bf16* l) {
  __builtin_amdgcn_global_load_lds(
      (const __attribute__((address_space(1))) void*)g,
      (__attribute__((address_space(3))) void*)l, 16, 0, 0);
}

// ---- cast fp32 -> interleaved hi|lo groups: out[g*16..+8)=hi8, [+8..+16)=lo8 ----
__global__ __launch_bounds__(256) void cast_interleave(const float* __restrict__ in,
                                                       bf16* __restrict__ out,
                                                       int ngroups) {
  int g = blockIdx.x * 256 + threadIdx.x;
  if (g >= ngroups) return;
  float4 v0 = *reinterpret_cast<const float4*>(in + (size_t)g * 8);
  float4 v1 = *reinterpret_cast<const float4*>(in + (size_t)g * 8 + 4);
  float f[8] = {v0.x, v0.y, v0.z, v0.w, v1.x, v1.y, v1.z, v1.w};
  short ho[8], lo[8];
#pragma unroll
  for (int j = 0; j < 8; ++j) {
    unsigned short hb = bfbits(f[j]);
    ho[j] = (short)hb;
    lo[j] = (short)bfbits(f[j] - bf2f(hb));
  }
  *reinterpret_cast<bf16x8*>(out + (size_t)g * 16)     = *reinterpret_cast<bf16x8*>(ho);
  *reinterpret_cast<bf16x8*>(out + (size_t)g * 16 + 8) = *reinterpret_cast<bf16x8*>(lo);
}

// ---- pack w_hh into per-WG fragment-major hi/lo --------------------------------
__global__ __launch_bounds__(256) void pack_whh_frag(const float* __restrict__ w,
                                                     bf16* __restrict__ ph,
                                                     bf16* __restrict__ pl) {
  int gid = blockIdx.x * 256 + threadIdx.x;   // 128*4096 groups
  int us  = gid >> 12;
  int rem = gid & 4095;
  int kcg = rem >> 7, n = (rem >> 6) & 1, l = rem & 63;
  int p = n * 16 + (l & 15);
  int q = p & 3, u = p >> 2;
  int k = kcg * 32 + (l >> 4) * 8;
  size_t src = (size_t)(q * 1024 + us * 8 + u) * HH + k;
  float4 v0 = *reinterpret_cast<const float4*>(w + src);
  float4 v1 = *reinterpret_cast<const float4*>(w + src + 4);
  float f[8] = {v0.x, v0.y, v0.z, v0.w, v1.x, v1.y, v1.z, v1.w};
  short ho[8], lo[8];
#pragma unroll
  for (int j = 0; j < 8; ++j) {
    unsigned short hb = bfbits(f[j]);
    ho[j] = (short)hb;
    lo[j] = (short)bfbits(f[j] - bf2f(hb));
  }
  *reinterpret_cast<bf16x8*>(ph + (size_t)gid * 8) = *reinterpret_cast<bf16x8*>(ho);
  *reinterpret_cast<bf16x8*>(pl + (size_t)gid * 8) = *reinterpret_cast<bf16x8*>(lo);
}

// ---- 3-term split-bf16 MFMA GEMM body, M=N=4096 fixed --------------------------
#define BM 128
#define BN 128
#define BKK 64

struct GemmArgs {
  const bf16* A; const bf16* B;
  const float* bias1; const float* bias2;
  float* C; int K; int alay;
};

template <int ALAY>
static __device__ __forceinline__ void gemm3_body(const GemmArgs G, bf16* smem,
                                                  int bidx, int nwg) {
  bf16 (*sAh)[BKK] = reinterpret_cast<bf16(*)[BKK]>(smem);
  bf16 (*sAl)[BKK] = reinterpret_cast<bf16(*)[BKK]>(smem + 8192);
  bf16 (*sBh)[BKK] = reinterpret_cast<bf16(*)[BKK]>(smem + 16384);
  bf16 (*sBl)[BKK] = reinterpret_cast<bf16(*)[BKK]>(smem + 24576);
  const int tid  = threadIdx.x;
  const int lane = tid & 63;
  const int wv   = tid >> 6;
  const int wr   = wv >> 1, wc = wv & 1;
  const int nbx  = 4096 / BN;
  // XCD-aware bijective swizzle (nwg % 8 == 0 by construction)
  const int swz  = (bidx & 7) * (nwg >> 3) + (bidx >> 3);
  const int bx   = swz % nbx, by = swz / nbx;
  const int l15  = lane & 15, l4 = lane >> 4;
  const int K    = G.K;
  const int K8   = K >> 3;

  f32x4 acc[4][4] = {};

  for (int k0 = 0; k0 < K; k0 += BKK) {
    __syncthreads();
#pragma unroll
    for (int i = 0; i < 4; ++i) {
      int f  = i * 256 + tid;
      int r  = f >> 3;
      int k8 = f & 7;
      bf16* dAh = smem + (size_t)f * 8;
      bf16* dAl = smem + 8192 + (size_t)f * 8;
      bf16* dBh = smem + 16384 + (size_t)f * 8;
      bf16* dBl = smem + 24576 + (size_t)f * 8;
      if constexpr (ALAY == 0) {
        const bf16* gA = G.A + ((size_t)(by * BM + r) * K8 + (k0 >> 3) + k8) * 16;
        gload_lds16(gA, dAh);
        gload_lds16(gA + 8, dAl);
      } else {
        int gr = by * BM + r;
        int t  = gr >> 6, b = gr & 63;
        int k8g = (k0 >> 3) + k8;
        int kcg = k8g >> 2, s4 = k8g & 3;
        const bf16* gA = G.A + (size_t)t * SLOT + (size_t)(b >> 4) * 32768
                       + (size_t)kcg * 1024 + (size_t)(s4 * 16 + (b & 15)) * 8;
        gload_lds16(gA, dAh);
        gload_lds16(gA + 512, dAl);
      }
      const bf16* gB = G.B + ((size_t)(bx * BN + r) * K8 + (k0 >> 3) + k8) * 16;
      gload_lds16(gB, dBh);
      gload_lds16(gB + 8, dBl);
    }
    __syncthreads();   // compiler drains vmcnt(0) for the lds-loads here
#pragma unroll
    for (int kk = 0; kk < BKK; kk += 32) {
      const int kf = kk + (l4 << 3);
      bf16x8 a_h[4], a_l[4], b_h[4], b_l[4];
#pragma unroll
      for (int m = 0; m < 4; ++m) {
        a_h[m] = *reinterpret_cast<const bf16x8*>(&sAh[wr * 64 + m * 16 + l15][kf]);
        a_l[m] = *reinterpret_cast<const bf16x8*>(&sAl[wr * 64 + m * 16 + l15][kf]);
      }
#pragma unroll
      for (int n = 0; n < 4; ++n) {
        b_h[n] = *reinterpret_cast<const bf16x8*>(&sBh[wc * 64 + n * 16 + l15][kf]);
        b_l[n] = *reinterpret_cast<const bf16x8*>(&sBl[wc * 64 + n * 16 + l15][kf]);
      }
#pragma unroll
      for (int m = 0; m < 4; ++m)
#pragma unroll
        for (int n = 0; n < 4; ++n) {
          acc[m][n] = __builtin_amdgcn_mfma_f32_16x16x32_bf16(a_h[m], b_h[n], acc[m][n], 0, 0, 0);
          acc[m][n] = __builtin_amdgcn_mfma_f32_16x16x32_bf16(a_l[m], b_h[n], acc[m][n], 0, 0, 0);
          acc[m][n] = __builtin_amdgcn_mfma_f32_16x16x32_bf16(a_h[m], b_l[n], acc[m][n], 0, 0, 0);
        }
    }
  }
#pragma unroll
  for (int n = 0; n < 4; ++n) {
    int col = bx * BN + wc * 64 + n * 16 + l15;
    float bv = G.bias1[col] + G.bias2[col];
#pragma unroll
    for (int m = 0; m < 4; ++m) {
      int row0 = by * BM + wr * 64 + m * 16 + l4 * 4;
      int t = row0 >> 6, b0 = row0 & 63;
      float4 v;
      v.x = acc[m][n][0] + bv;
      v.y = acc[m][n][1] + bv;
      v.z = acc[m][n][2] + bv;
      v.w = acc[m][n][3] + bv;
      *reinterpret_cast<float4*>(G.C + (size_t)t * (NG4 * 64) + (size_t)col * 64 + b0) = v;
    }
  }
}

// dual-role GEMM: blocks [0,g0) run GA, [g0,grid) run GB
__global__ __launch_bounds__(256) void gemm_dual(GemmArgs GA, GemmArgs GB, int g0) {
  __shared__ bf16 smem[32768];
  const int b = (int)blockIdx.x;
  if (b < g0) {
    if (GA.alay) gemm3_body<1>(GA, smem, b, g0);
    else         gemm3_body<0>(GA, smem, b, g0);
  } else {
    if (GB.alay) gemm3_body<1>(GB, smem, b - g0, (int)gridDim.x - g0);
    else         gemm3_body<0>(GB, smem, b - g0, (int)gridDim.x - g0);
  }
}

// ---- scan parameter set (one layer-chunk) --------------------------------------
struct ScanArgs {
  const bf16* wpkh; const bf16* wpkl;   // [128][32768] packed recurrent weights
  const float* xgT;                     // [CT][4096][64]
  bf16* hbase;                          // chain: CT+1 slots (slot s read at step s)
  float* cst;                           // [64][1024]
  int* flags;                           // [NWG*4], monotonic across dispatches
  float* outp;                          // [CT*64][1024] or null
  int fbase;                            // cumulative steps already signaled
};

// ---- persistent chunk scan, dual-role, overlapped barrier ----------------------
// kh0 waves: reduce+pointwise+store, then per-wave vmcnt drain + sub-flag signal,
// then next-step xq prefetch. kh1 waves: poll all 512 sub-flags concurrently.
__global__ __launch_bounds__(512, 1) void lstm_scan(ScanArgs PA, ScanArgs PB,
                                                    int nwg0, int CT) {
  __shared__ bf16  sW[65536];        // hi at [0,32768), lo at [32768,65536)
  __shared__ float gred[4][16][33];

  const int role = (blockIdx.x >= nwg0) ? 1 : 0;
  const ScanArgs P = role ? PB : PA;
  const int wg   = blockIdx.x - (role ? nwg0 : 0);

  const int tid  = threadIdx.x;
  const int lane = tid & 63;
  const int wv   = tid >> 6;
  const int m    = wv >> 1;
  const int kh   = wv & 1;
  const int j0   = wg * 8;
  const int l15  = lane & 15, l4 = lane >> 4;

  // stage weights into LDS once
  {
    const bf16x8* srcH = reinterpret_cast<const bf16x8*>(P.wpkh + (size_t)wg * 32768);
    const bf16x8* srcL = reinterpret_cast<const bf16x8*>(P.wpkl + (size_t)wg * 32768);
    bf16x8* dH = reinterpret_cast<bf16x8*>(sW);
    bf16x8* dL = reinterpret_cast<bf16x8*>(sW + 32768);
    for (int i = tid; i < 4096; i += 512) { dH[i] = srcH[i]; dL[i] = srcL[i]; }
  }

  // pointwise ownership (kh==0 waves): batch = m*16+bl, units j0+2*up, +1
  const int bl = lane & 15;
  const int up = lane >> 4;
  const int pbatch = m * 16 + bl;
  float cS0 = 0.f, cS1 = 0.f;
  float xq[2][4];
  if (kh == 0) {
    cS0 = P.cst[(size_t)pbatch * HH + j0 + 2 * up];
    cS1 = P.cst[(size_t)pbatch * HH + j0 + 2 * up + 1];
    // xq for step 0
#pragma unroll
    for (int d = 0; d < 2; ++d) {
      int j = j0 + 2 * up + d;
#pragma unroll
      for (int q = 0; q < 4; ++q)
        xq[d][q] = P.xgT[(size_t)(q * 1024 + j) * 64 + pbatch];
    }
  }
  __syncthreads();

  for (int s = 0; s < CT; ++s) {
    const bf16* hrd = P.hbase + (size_t)s * SLOT;
    bf16*       hwr = P.hbase + (size_t)(s + 1) * SLOT;

    // dense h loads (cached; L2 shared across the XCD's WGs)
    const bf16* hp = hrd + (size_t)m * 32768 + (size_t)(kh * 16) * 1024 + (size_t)lane * 8;

    f32x4 acc0 = {}, acc1 = {};
#pragma unroll
    for (int T = 0; T < 16; ++T) {
      const int kcg_ = kh * 16 + T;
      bf16x8 hh = *reinterpret_cast<const bf16x8*>(hp + T * 1024);
      bf16x8 hl = *reinterpret_cast<const bf16x8*>(hp + T * 1024 + 512);
      bf16x8 bh0 = *reinterpret_cast<const bf16x8*>(sW + ((kcg_ * 2 + 0) * 64 + lane) * 8);
      bf16x8 bw0 = *reinterpret_cast<const bf16x8*>(sW + 32768 + ((kcg_ * 2 + 0) * 64 + lane) * 8);
      bf16x8 bh1 = *reinterpret_cast<const bf16x8*>(sW + ((kcg_ * 2 + 1) * 64 + lane) * 8);
      bf16x8 bw1 = *reinterpret_cast<const bf16x8*>(sW + 32768 + ((kcg_ * 2 + 1) * 64 + lane) * 8);
      acc0 = __builtin_amdgcn_mfma_f32_16x16x32_bf16(hh, bh0, acc0, 0, 0, 0);
      acc0 = __builtin_amdgcn_mfma_f32_16x16x32_bf16(hl, bh0, acc0, 0, 0, 0);
      acc0 = __builtin_amdgcn_mfma_f32_16x16x32_bf16(hh, bw0, acc0, 0, 0, 0);
      acc1 = __builtin_amdgcn_mfma_f32_16x16x32_bf16(hh, bh1, acc1, 0, 0, 0);
      acc1 = __builtin_amdgcn_mfma_f32_16x16x32_bf16(hl, bh1, acc1, 0, 0, 0);
      acc1 = __builtin_amdgcn_mfma_f32_16x16x32_bf16(hh, bw1, acc1, 0, 0, 0);
    }

    // reduction hand-off: kh1 stores partials, sync, then roles diverge
    if (kh == 1) {
#pragma unroll
      for (int r = 0; r < 4; ++r) {
        gred[m][l4 * 4 + r][l15]      = acc0[r];
        gred[m][l4 * 4 + r][16 + l15] = acc1[r];
      }
    }
    __syncthreads();   // (#1) gred partials visible to kh0

    if (kh == 0) {
#pragma unroll
      for (int r = 0; r < 4; ++r) {
        int rr = l4 * 4 + r;
        acc0[r] += gred[m][rr][l15];
        acc1[r] += gred[m][rr][16 + l15];
        gred[m][rr][l15]      = acc0[r];
        gred[m][rr][16 + l15] = acc1[r];
      }
      asm volatile("s_waitcnt lgkmcnt(0)" ::: "memory");

      float hv[2];
#pragma unroll
      for (int d = 0; d < 2; ++d) {
        int uu = 2 * up + d;
        float iv = gred[m][bl][uu * 4 + 0] + xq[d][0];
        float fv = gred[m][bl][uu * 4 + 1] + xq[d][1];
        float gv = gred[m][bl][uu * 4 + 2] + xq[d][2];
        float ov = gred[m][bl][uu * 4 + 3] + xq[d][3];
        iv = 1.f / (1.f + __expf(-iv));
        fv = 1.f / (1.f + __expf(-fv));
        gv = tanhf(gv);
        ov = 1.f / (1.f + __expf(-ov));
        float cv = fv * (d ? cS1 : cS0) + iv * gv;
        if (d) cS1 = cv; else cS0 = cv;
        hv[d] = ov * tanhf(cv);
      }
      unsigned short h0b = bfbits(hv[0]), h1b = bfbits(hv[1]);
      unsigned short l0b = bfbits(hv[0] - bf2f(h0b));
      unsigned short l1b = bfbits(hv[1] - bf2f(h1b));
      unsigned hiW = (unsigned)h0b | ((unsigned)h1b << 16);
      unsigned loW = (unsigned)l0b | ((unsigned)l1b << 16);
      // dense store: kcg = wg>>2, lane' = (wg&3)*16+bl, elems 2up(+1); lo at +512
      size_t wo = (size_t)m * 32768 + (size_t)(wg >> 2) * 1024
                + (size_t)((wg & 3) * 16 + bl) * 8 + 2 * up;
      st_agent4(hwr + wo, hiW);
      st_agent4(hwr + wo + 512, loW);
      if (s == CT - 1) {           // seed slot 0 for the next chunk (carry)
        st_agent4(P.hbase + wo, hiW);
        st_agent4(P.hbase + wo + 512, loW);
      }
      if (P.outp) {
        float2 o2 = make_float2(hv[0], hv[1]);
        *reinterpret_cast<float2*>(P.outp + (size_t)(s * 64 + pbatch) * HH + j0 + 2 * up) = o2;
      }
      if (s + 1 < CT) {
        // per-wave drain of the h stores, then signal this wave's sub-flag
        asm volatile("s_waitcnt vmcnt(0)" ::: "memory");
        if (lane == 0)
          __hip_atomic_store(&P.flags[wg * 4 + m], P.fbase + s + 1,
                             __ATOMIC_RELAXED, __HIP_MEMORY_SCOPE_AGENT);
        // prefetch xq for the next step (overlaps the barrier wait)
        const float* xgn = P.xgT + (size_t)(s + 1) * (NG4 * 64);
#pragma unroll
        for (int d = 0; d < 2; ++d) {
          int j = j0 + 2 * up + d;
#pragma unroll
          for (int q = 0; q < 4; ++q)
            xq[d][q] = xgn[(size_t)(q * 1024 + j) * 64 + pbatch];
        }
      }
    } else if (s + 1 < CT) {
      // kh1 waves: poll all sub-flags (2 per thread) while kh0 computes
      const int widx = (wv >> 1) * 64 + lane;   // 0..255
      const int tgt  = P.fbase + s + 1;
      while (__hip_atomic_load(&P.flags[widx], __ATOMIC_RELAXED,
                               __HIP_MEMORY_SCOPE_AGENT) < tgt)
        __builtin_amdgcn_s_sleep(1);
      while (__hip_atomic_load(&P.flags[widx + 256], __ATOMIC_RELAXED,
                               __HIP_MEMORY_SCOPE_AGENT) < tgt)
        __builtin_amdgcn_s_sleep(1);
    }

    if (s + 1 < CT) __syncthreads();   // (#2) join: all flags seen + own work done
  }

  if (kh == 0) {
    P.cst[(size_t)pbatch * HH + j0 + 2 * up]     = cS0;
    P.cst[(size_t)pbatch * HH + j0 + 2 * up + 1] = cS1;
  }
}

extern "C" void kernel_launch(void* const* d_in, const int* in_sizes, int n_in,
                              void* d_out, int out_size, void* d_ws, size_t ws_size,
                              hipStream_t stream) {
  const float* x    = (const float*)d_in[0];
  const float* wih0 = (const float*)d_in[1];
  const float* whh0 = (const float*)d_in[2];
  const float* bih0 = (const float*)d_in[3];
  const float* bhh0 = (const float*)d_in[4];
  const float* wih1 = (const float*)d_in[5];
  const float* whh1 = (const float*)d_in[6];
  const float* bih1 = (const float*)d_in[7];
  const float* bhh1 = (const float*)d_in[8];
  float* out = (float*)d_out;

  int ct = 64;
  for (;;) {
    size_t fixed = (size_t)TT * BB * DD * 2 * 2        // xc interleaved
                 + (size_t)NG4 * DD * 2 * 2            // w0c interleaved
                 + (size_t)NG4 * HH * 2 * 2            // w1c interleaved
                 + (size_t)NG4 * HH * 2 * 2 * 2        // packed whh hi/lo x2 layers
                 + (size_t)2 * BB * HH * 4             // c states
                 + ((size_t)1 << 18);
    size_t var = (size_t)2 * ct * BB * NG4 * 4         // xgT x2
               + (size_t)2 * (ct + 1) * SLOTB;         // two h chains
    if (fixed + var <= ws_size || ct == 8) break;
    ct >>= 1;
  }
  const int nch = TT / ct;

  char* ws = (char*)d_ws;
  size_t off = 0;
  auto alloc = [&](size_t bytes) -> char* {
    char* p = ws + off;
    off += (bytes + 255) & ~(size_t)255;
    return p;
  };
  bf16*  xc    = (bf16*)alloc((size_t)TT * BB * DD * 2 * 2);
  bf16*  w0c   = (bf16*)alloc((size_t)NG4 * DD * 2 * 2);
  bf16*  w1c   = (bf16*)alloc((size_t)NG4 * HH * 2 * 2);
  bf16*  wpk0h = (bf16*)alloc((size_t)NG4 * HH * 2);
  bf16*  wpk0l = (bf16*)alloc((size_t)NG4 * HH * 2);
  bf16*  wpk1h = (bf16*)alloc((size_t)NG4 * HH * 2);
  bf16*  wpk1l = (bf16*)alloc((size_t)NG4 * HH * 2);
  bf16*  svc0  = (bf16*)alloc((size_t)(ct + 1) * SLOTB);  // layer-0 h chain
  bf16*  svc1  = (bf16*)alloc((size_t)(ct + 1) * SLOTB);  // layer-1 h chain
  float* xgT0  = (float*)alloc((size_t)ct * BB * NG4 * 4);
  float* xgT1  = (float*)alloc((size_t)ct * BB * NG4 * 4);
  float* c0    = (float*)alloc((size_t)BB * HH * 4);
  float* c1    = (float*)alloc((size_t)BB * HH * 4);
  int*   flagsA = (int*)alloc((size_t)NWG * 4 * 4);
  int*   flagsB = (int*)alloc((size_t)NWG * 4 * 4);

  cast_interleave<<<(TT * BB * DD / 8 + 255) / 256, 256, 0, stream>>>(x, xc, TT * BB * DD / 8);
  cast_interleave<<<(NG4 * DD / 8 + 255) / 256, 256, 0, stream>>>(wih0, w0c, NG4 * DD / 8);
  cast_interleave<<<(NG4 * HH / 8 + 255) / 256, 256, 0, stream>>>(wih1, w1c, NG4 * HH / 8);
  pack_whh_frag<<<2048, 256, 0, stream>>>(whh0, wpk0h, wpk0l);
  pack_whh_frag<<<2048, 256, 0, stream>>>(whh1, wpk1h, wpk1l);

  hipMemsetAsync(svc0, 0, SLOTB, stream);             // h0 initial state (slot 0)
  hipMemsetAsync(svc1, 0, SLOTB, stream);             // h1 initial state (slot 0)
  hipMemsetAsync(c0, 0, (size_t)BB * HH * 4, stream);
  hipMemsetAsync(c1, 0, (size_t)BB * HH * 4, stream);
  hipMemsetAsync(flagsA, 0, (size_t)NWG * 4 * 4, stream); // once; monotonic after
  hipMemsetAsync(flagsB, 0, (size_t)NWG * 4 * 4, stream);

  const int gemmGrid = (ct * BB / BM) * (NG4 / BN);   // 1024 at ct=64
  int fb0 = 0, fb1 = 0;

  ScanArgs a0 = {wpk0h, wpk0l, xgT0, svc0, c0, flagsB, (float*)nullptr, 0};  // layer-0
  ScanArgs a1 = {wpk1h, wpk1l, xgT1, svc1, c1, flagsA, (float*)nullptr, 0};  // layer-1

  // prologue: layer-0 projection chunk 0 + solo scan
  GemmArgs g0c0 = {xc, w0c, bih0, bhh0, xgT0, DD, 0};
  gemm_dual<<<gemmGrid, 256, 0, stream>>>(g0c0, g0c0, gemmGrid);
  a0.fbase = fb0;
  lstm_scan<<<NWG, 512, 0, stream>>>(a0, a0, NWG, ct);
  fb0 += ct;

  for (int c = 0; c < nch; ++c) {
    GemmArgs g1 = {svc0 + SLOT, w1c, bih1, bhh1, xgT1, HH, 1};   // layer-1 proj c
    a1.outp = out + (size_t)c * ct * BB * HH;
    if (c + 1 < nch) {
      GemmArgs g0n = {xc + (size_t)(c + 1) * ct * BB * DD * 2,
                      w0c, bih0, bhh0, xgT0, DD, 0};             // layer-0 proj c+1
      gemm_dual<<<2 * gemmGrid, 256, 0, stream>>>(g1, g0n, gemmGrid);
      a1.fbase = fb1;
      a0.fbase = fb0;
      // fused: WGs 0..127 = layer-1 chunk c ; WGs 128..255 = layer-0 chunk c+1
      lstm_scan<<<2 * NWG, 512, 0, stream>>>(a1, a0, NWG, ct);
      fb1 += ct; fb0 += ct;
    } else {
      gemm_dual<<<gemmGrid, 256, 0, stream>>>(g1, g1, gemmGrid);
      a1.fbase = fb1;
      lstm_scan<<<NWG, 512, 0, stream>>>(a1, a1, NWG, ct);
      fb1 += ct;
    }
  }
}

// Round 13
// 7926.311 us; speedup vs baseline: 1.1057x; 1.1057x over previous
//
#include <hip/hip_runtime.h>
#include <hip/hip_bf16.h>

#define TT 512
#define BB 64
#define DD 1024
#define HH 1024
#define NG4 4096
#define NWG 128
#define SLOT 131072       // bf16 elems per h slot (4 blocks x 32768)
#define SLOTB 262144      // bytes per h slot

typedef short bf16x8 __attribute__((ext_vector_type(8)));
typedef float f32x4 __attribute__((ext_vector_type(4)));
typedef __hip_bfloat16 bf16;

static __device__ __forceinline__ unsigned short bfbits(float f) {
  bf16 h = __float2bfloat16(f);
  return *reinterpret_cast<unsigned short*>(&h);
}
static __device__ __forceinline__ float bf2f(unsigned short u) {
  bf16 h = *reinterpret_cast<bf16*>(&u);
  return __bfloat162float(h);
}
static __device__ __forceinline__ void st_agent4(void* p, unsigned v) {
  __hip_atomic_store((unsigned*)p, v, __ATOMIC_RELAXED, __HIP_MEMORY_SCOPE_AGENT);
}
// async global->LDS, 16B per lane; dest must be lane-linear (base + lane*16)
static __device__ __forceinline__ void gload_lds16(const bf16* g, bf16* l) {
  __builtin_amdgcn_global_load_lds(
      (const __attribute__((address_space(1))) void*)g,
      (__attribute__((address_space(3))) void*)l, 16, 0, 0);
}

// ---- cast fp32 -> interleaved hi|lo groups: out[g*16..+8)=hi8, [+8..+16)=lo8 ----
__global__ __launch_bounds__(256) void cast_interleave(const float* __restrict__ in,
                                                       bf16* __restrict__ out,
                                                       int ngroups) {
  int g = blockIdx.x * 256 + threadIdx.x;
  if (g >= ngroups) return;
  float4 v0 = *reinterpret_cast<const float4*>(in + (size_t)g * 8);
  float4 v1 = *reinterpret_cast<const float4*>(in + (size_t)g * 8 + 4);
  float f[8] = {v0.x, v0.y, v0.z, v0.w, v1.x, v1.y, v1.z, v1.w};
  short ho[8], lo[8];
#pragma unroll
  for (int j = 0; j < 8; ++j) {
    unsigned short hb = bfbits(f[j]);
    ho[j] = (short)hb;
    lo[j] = (short)bfbits(f[j] - bf2f(hb));
  }
  *reinterpret_cast<bf16x8*>(out + (size_t)g * 16)     = *reinterpret_cast<bf16x8*>(ho);
  *reinterpret_cast<bf16x8*>(out + (size_t)g * 16 + 8) = *reinterpret_cast<bf16x8*>(lo);
}

// ---- pack w_hh into per-WG fragment-major hi/lo --------------------------------
__global__ __launch_bounds__(256) void pack_whh_frag(const float* __restrict__ w,
                                                     bf16* __restrict__ ph,
                                                     bf16* __restrict__ pl) {
  int gid = blockIdx.x * 256 + threadIdx.x;   // 128*4096 groups
  int us  = gid >> 12;
  int rem = gid & 4095;
  int kcg = rem >> 7, n = (rem >> 6) & 1, l = rem & 63;
  int p = n * 16 + (l & 15);
  int q = p & 3, u = p >> 2;
  int k = kcg * 32 + (l >> 4) * 8;
  size_t src = (size_t)(q * 1024 + us * 8 + u) * HH + k;
  float4 v0 = *reinterpret_cast<const float4*>(w + src);
  float4 v1 = *reinterpret_cast<const float4*>(w + src + 4);
  float f[8] = {v0.x, v0.y, v0.z, v0.w, v1.x, v1.y, v1.z, v1.w};
  short ho[8], lo[8];
#pragma unroll
  for (int j = 0; j < 8; ++j) {
    unsigned short hb = bfbits(f[j]);
    ho[j] = (short)hb;
    lo[j] = (short)bfbits(f[j] - bf2f(hb));
  }
  *reinterpret_cast<bf16x8*>(ph + (size_t)gid * 8) = *reinterpret_cast<bf16x8*>(ho);
  *reinterpret_cast<bf16x8*>(pl + (size_t)gid * 8) = *reinterpret_cast<bf16x8*>(lo);
}

// ---- 3-term split-bf16 MFMA GEMM body, M=N=4096 fixed --------------------------
#define BM 128
#define BN 128
#define BKK 64

struct GemmArgs {
  const bf16* A; const bf16* B;
  const float* bias1; const float* bias2;
  float* C; int K; int alay;
};

template <int ALAY>
static __device__ __forceinline__ void gemm3_body(const GemmArgs G, bf16* smem,
                                                  int bidx, int nwg) {
  bf16 (*sAh)[BKK] = reinterpret_cast<bf16(*)[BKK]>(smem);
  bf16 (*sAl)[BKK] = reinterpret_cast<bf16(*)[BKK]>(smem + 8192);
  bf16 (*sBh)[BKK] = reinterpret_cast<bf16(*)[BKK]>(smem + 16384);
  bf16 (*sBl)[BKK] = reinterpret_cast<bf16(*)[BKK]>(smem + 24576);
  const int tid  = threadIdx.x;
  const int lane = tid & 63;
  const int wv   = tid >> 6;
  const int wr   = wv >> 1, wc = wv & 1;
  const int nbx  = 4096 / BN;
  // XCD-aware bijective swizzle (nwg % 8 == 0 by construction)
  const int swz  = (bidx & 7) * (nwg >> 3) + (bidx >> 3);
  const int bx   = swz % nbx, by = swz / nbx;
  const int l15  = lane & 15, l4 = lane >> 4;
  const int K    = G.K;
  const int K8   = K >> 3;

  f32x4 acc[4][4] = {};

  for (int k0 = 0; k0 < K; k0 += BKK) {
    __syncthreads();
#pragma unroll
    for (int i = 0; i < 4; ++i) {
      int f  = i * 256 + tid;
      int r  = f >> 3;
      int k8 = f & 7;
      bf16* dAh = smem + (size_t)f * 8;
      bf16* dAl = smem + 8192 + (size_t)f * 8;
      bf16* dBh = smem + 16384 + (size_t)f * 8;
      bf16* dBl = smem + 24576 + (size_t)f * 8;
      if constexpr (ALAY == 0) {
        const bf16* gA = G.A + ((size_t)(by * BM + r) * K8 + (k0 >> 3) + k8) * 16;
        gload_lds16(gA, dAh);
        gload_lds16(gA + 8, dAl);
      } else {
        int gr = by * BM + r;
        int t  = gr >> 6, b = gr & 63;
        int k8g = (k0 >> 3) + k8;
        int kcg = k8g >> 2, s4 = k8g & 3;
        const bf16* gA = G.A + (size_t)t * SLOT + (size_t)(b >> 4) * 32768
                       + (size_t)kcg * 1024 + (size_t)(s4 * 16 + (b & 15)) * 8;
        gload_lds16(gA, dAh);
        gload_lds16(gA + 512, dAl);
      }
      const bf16* gB = G.B + ((size_t)(bx * BN + r) * K8 + (k0 >> 3) + k8) * 16;
      gload_lds16(gB, dBh);
      gload_lds16(gB + 8, dBl);
    }
    __syncthreads();   // compiler drains vmcnt(0) for the lds-loads here
#pragma unroll
    for (int kk = 0; kk < BKK; kk += 32) {
      const int kf = kk + (l4 << 3);
      bf16x8 a_h[4], a_l[4], b_h[4], b_l[4];
#pragma unroll
      for (int m = 0; m < 4; ++m) {
        a_h[m] = *reinterpret_cast<const bf16x8*>(&sAh[wr * 64 + m * 16 + l15][kf]);
        a_l[m] = *reinterpret_cast<const bf16x8*>(&sAl[wr * 64 + m * 16 + l15][kf]);
      }
#pragma unroll
      for (int n = 0; n < 4; ++n) {
        b_h[n] = *reinterpret_cast<const bf16x8*>(&sBh[wc * 64 + n * 16 + l15][kf]);
        b_l[n] = *reinterpret_cast<const bf16x8*>(&sBl[wc * 64 + n * 16 + l15][kf]);
      }
#pragma unroll
      for (int m = 0; m < 4; ++m)
#pragma unroll
        for (int n = 0; n < 4; ++n) {
          acc[m][n] = __builtin_amdgcn_mfma_f32_16x16x32_bf16(a_h[m], b_h[n], acc[m][n], 0, 0, 0);
          acc[m][n] = __builtin_amdgcn_mfma_f32_16x16x32_bf16(a_l[m], b_h[n], acc[m][n], 0, 0, 0);
          acc[m][n] = __builtin_amdgcn_mfma_f32_16x16x32_bf16(a_h[m], b_l[n], acc[m][n], 0, 0, 0);
        }
    }
  }
#pragma unroll
  for (int n = 0; n < 4; ++n) {
    int col = bx * BN + wc * 64 + n * 16 + l15;
    float bv = G.bias1[col] + G.bias2[col];
#pragma unroll
    for (int m = 0; m < 4; ++m) {
      int row0 = by * BM + wr * 64 + m * 16 + l4 * 4;
      int t = row0 >> 6, b0 = row0 & 63;
      float4 v;
      v.x = acc[m][n][0] + bv;
      v.y = acc[m][n][1] + bv;
      v.z = acc[m][n][2] + bv;
      v.w = acc[m][n][3] + bv;
      *reinterpret_cast<float4*>(G.C + (size_t)t * (NG4 * 64) + (size_t)col * 64 + b0) = v;
    }
  }
}

// dual-role GEMM: blocks [0,g0) run GA, [g0,grid) run GB
__global__ __launch_bounds__(256) void gemm_dual(GemmArgs GA, GemmArgs GB, int g0) {
  __shared__ bf16 smem[32768];
  const int b = (int)blockIdx.x;
  if (b < g0) {
    if (GA.alay) gemm3_body<1>(GA, smem, b, g0);
    else         gemm3_body<0>(GA, smem, b, g0);
  } else {
    if (GB.alay) gemm3_body<1>(GB, smem, b - g0, (int)gridDim.x - g0);
    else         gemm3_body<0>(GB, smem, b - g0, (int)gridDim.x - g0);
  }
}

// ---- scan parameter set (one layer-chunk) --------------------------------------
struct ScanArgs {
  const bf16* wpkh; const bf16* wpkl;   // [128][32768] packed recurrent weights
  const float* xgT;                     // [CT][4096][64]
  bf16* hbase;                          // chain: CT+1 slots (slot s read at step s)
  float* cst;                           // [64][1024]
  int* flags;                           // [NWG], monotonic across dispatches
  float* outp;                          // [CT*64][1024] or null
  int fbase;                            // cumulative steps already signaled
};

// ---- persistent chunk scan, dual-role, centralized barrier (r11 form) ----------
__global__ __launch_bounds__(512, 1) void lstm_scan(ScanArgs PA, ScanArgs PB,
                                                    int nwg0, int CT) {
  __shared__ bf16  sW[65536];        // hi at [0,32768), lo at [32768,65536)
  __shared__ float gred[4][16][33];

  const int role = (blockIdx.x >= nwg0) ? 1 : 0;
  const ScanArgs P = role ? PB : PA;
  const int wg   = blockIdx.x - (role ? nwg0 : 0);

  const int tid  = threadIdx.x;
  const int lane = tid & 63;
  const int wv   = tid >> 6;
  const int m    = wv >> 1;
  const int kh   = wv & 1;
  const int j0   = wg * 8;
  const int l15  = lane & 15, l4 = lane >> 4;

  // stage weights into LDS once
  {
    const bf16x8* srcH = reinterpret_cast<const bf16x8*>(P.wpkh + (size_t)wg * 32768);
    const bf16x8* srcL = reinterpret_cast<const bf16x8*>(P.wpkl + (size_t)wg * 32768);
    bf16x8* dH = reinterpret_cast<bf16x8*>(sW);
    bf16x8* dL = reinterpret_cast<bf16x8*>(sW + 32768);
    for (int i = tid; i < 4096; i += 512) { dH[i] = srcH[i]; dL[i] = srcL[i]; }
  }

  // pointwise ownership (kh==0 waves): batch = m*16+bl, units j0+2*up, +1
  const int bl = lane & 15;
  const int up = lane >> 4;
  const int pbatch = m * 16 + bl;
  float cS0 = 0.f, cS1 = 0.f;
  if (kh == 0) {
    cS0 = P.cst[(size_t)pbatch * HH + j0 + 2 * up];
    cS1 = P.cst[(size_t)pbatch * HH + j0 + 2 * up + 1];
  }
  __syncthreads();

  for (int s = 0; s < CT; ++s) {
    const bf16* hrd = P.hbase + (size_t)s * SLOT;
    bf16*       hwr = P.hbase + (size_t)(s + 1) * SLOT;

    // xq prefetch (kh==0 waves), normal cached loads
    float xq[2][4];
    const float* xgs = P.xgT + (size_t)s * (NG4 * 64);
    if (kh == 0) {
#pragma unroll
      for (int d = 0; d < 2; ++d) {
        int j = j0 + 2 * up + d;
#pragma unroll
        for (int q = 0; q < 4; ++q)
          xq[d][q] = xgs[(size_t)(q * 1024 + j) * 64 + pbatch];
      }
    }

    // dense h loads (cached; L2 shared across the XCD's WGs)
    const bf16* hp = hrd + (size_t)m * 32768 + (size_t)(kh * 16) * 1024 + (size_t)lane * 8;

    f32x4 acc0 = {}, acc1 = {};
#pragma unroll
    for (int T = 0; T < 16; ++T) {
      const int kcg_ = kh * 16 + T;
      bf16x8 hh = *reinterpret_cast<const bf16x8*>(hp + T * 1024);
      bf16x8 hl = *reinterpret_cast<const bf16x8*>(hp + T * 1024 + 512);
      bf16x8 bh0 = *reinterpret_cast<const bf16x8*>(sW + ((kcg_ * 2 + 0) * 64 + lane) * 8);
      bf16x8 bw0 = *reinterpret_cast<const bf16x8*>(sW + 32768 + ((kcg_ * 2 + 0) * 64 + lane) * 8);
      bf16x8 bh1 = *reinterpret_cast<const bf16x8*>(sW + ((kcg_ * 2 + 1) * 64 + lane) * 8);
      bf16x8 bw1 = *reinterpret_cast<const bf16x8*>(sW + 32768 + ((kcg_ * 2 + 1) * 64 + lane) * 8);
      acc0 = __builtin_amdgcn_mfma_f32_16x16x32_bf16(hh, bh0, acc0, 0, 0, 0);
      acc0 = __builtin_amdgcn_mfma_f32_16x16x32_bf16(hl, bh0, acc0, 0, 0, 0);
      acc0 = __builtin_amdgcn_mfma_f32_16x16x32_bf16(hh, bw0, acc0, 0, 0, 0);
      acc1 = __builtin_amdgcn_mfma_f32_16x16x32_bf16(hh, bh1, acc1, 0, 0, 0);
      acc1 = __builtin_amdgcn_mfma_f32_16x16x32_bf16(hl, bh1, acc1, 0, 0, 0);
      acc1 = __builtin_amdgcn_mfma_f32_16x16x32_bf16(hh, bw1, acc1, 0, 0, 0);
    }

    // one-round reduction: kh==1 waves store partials, kh==0 add
    if (kh == 1) {
#pragma unroll
      for (int r = 0; r < 4; ++r) {
        gred[m][l4 * 4 + r][l15]      = acc0[r];
        gred[m][l4 * 4 + r][16 + l15] = acc1[r];
      }
    }
    __syncthreads();
    if (kh == 0) {
#pragma unroll
      for (int r = 0; r < 4; ++r) {
        int rr = l4 * 4 + r;
        acc0[r] += gred[m][rr][l15];
        acc1[r] += gred[m][rr][16 + l15];
        gred[m][rr][l15]      = acc0[r];
        gred[m][rr][16 + l15] = acc1[r];
      }
      asm volatile("s_waitcnt lgkmcnt(0)" ::: "memory");

      float hv[2];
#pragma unroll
      for (int d = 0; d < 2; ++d) {
        int uu = 2 * up + d;
        float iv = gred[m][bl][uu * 4 + 0] + xq[d][0];
        float fv = gred[m][bl][uu * 4 + 1] + xq[d][1];
        float gv = gred[m][bl][uu * 4 + 2] + xq[d][2];
        float ov = gred[m][bl][uu * 4 + 3] + xq[d][3];
        iv = 1.f / (1.f + __expf(-iv));
        fv = 1.f / (1.f + __expf(-fv));
        gv = tanhf(gv);
        ov = 1.f / (1.f + __expf(-ov));
        float cv = fv * (d ? cS1 : cS0) + iv * gv;
        if (d) cS1 = cv; else cS0 = cv;
        hv[d] = ov * tanhf(cv);
      }
      unsigned short h0b = bfbits(hv[0]), h1b = bfbits(hv[1]);
      unsigned short l0b = bfbits(hv[0] - bf2f(h0b));
      unsigned short l1b = bfbits(hv[1] - bf2f(h1b));
      unsigned hiW = (unsigned)h0b | ((unsigned)h1b << 16);
      unsigned loW = (unsigned)l0b | ((unsigned)l1b << 16);
      // dense store: kcg = wg>>2, lane' = (wg&3)*16+bl, elems 2up(+1); lo at +512
      size_t wo = (size_t)m * 32768 + (size_t)(wg >> 2) * 1024
                + (size_t)((wg & 3) * 16 + bl) * 8 + 2 * up;
      st_agent4(hwr + wo, hiW);
      st_agent4(hwr + wo + 512, loW);
      if (s == CT - 1) {           // seed slot 0 for the next chunk (carry)
        st_agent4(P.hbase + wo, hiW);
        st_agent4(P.hbase + wo + 512, loW);
      }
      if (P.outp) {
        float2 o2 = make_float2(hv[0], hv[1]);
        *reinterpret_cast<float2*>(P.outp + (size_t)(s * 64 + pbatch) * HH + j0 + 2 * up) = o2;
      }
    }

    // per-role grid barrier (skip after last step): monotonic flags, no resets
    if (s + 1 < CT) {
      __syncthreads();   // drains vmcnt: h stores at coherent point before signal
      if (tid == 0)
        __hip_atomic_store(&P.flags[wg], P.fbase + s + 1, __ATOMIC_RELAXED, __HIP_MEMORY_SCOPE_AGENT);
      if (tid < NWG) {
        while (__hip_atomic_load(&P.flags[tid], __ATOMIC_RELAXED, __HIP_MEMORY_SCOPE_AGENT) < P.fbase + s + 1)
          __builtin_amdgcn_s_sleep(1);
      }
      __syncthreads();   // compiler+HW barrier: h loads can't hoist above the poll
    }
  }

  if (kh == 0) {
    P.cst[(size_t)pbatch * HH + j0 + 2 * up]     = cS0;
    P.cst[(size_t)pbatch * HH + j0 + 2 * up + 1] = cS1;
  }
}

extern "C" void kernel_launch(void* const* d_in, const int* in_sizes, int n_in,
                              void* d_out, int out_size, void* d_ws, size_t ws_size,
                              hipStream_t stream) {
  const float* x    = (const float*)d_in[0];
  const float* wih0 = (const float*)d_in[1];
  const float* whh0 = (const float*)d_in[2];
  const float* bih0 = (const float*)d_in[3];
  const float* bhh0 = (const float*)d_in[4];
  const float* wih1 = (const float*)d_in[5];
  const float* whh1 = (const float*)d_in[6];
  const float* bih1 = (const float*)d_in[7];
  const float* bhh1 = (const float*)d_in[8];
  float* out = (float*)d_out;

  int ct = 64;
  for (;;) {
    size_t fixed = (size_t)TT * BB * DD * 2 * 2        // xc interleaved
                 + (size_t)NG4 * DD * 2 * 2            // w0c interleaved
                 + (size_t)NG4 * HH * 2 * 2            // w1c interleaved
                 + (size_t)NG4 * HH * 2 * 2 * 2        // packed whh hi/lo x2 layers
                 + (size_t)2 * BB * HH * 4             // c states
                 + ((size_t)1 << 18);
    size_t var = (size_t)2 * ct * BB * NG4 * 4         // xgT x2
               + (size_t)2 * (ct + 1) * SLOTB;         // two h chains
    if (fixed + var <= ws_size || ct == 8) break;
    ct >>= 1;
  }
  const int nch = TT / ct;

  char* ws = (char*)d_ws;
  size_t off = 0;
  auto alloc = [&](size_t bytes) -> char* {
    char* p = ws + off;
    off += (bytes + 255) & ~(size_t)255;
    return p;
  };
  bf16*  xc    = (bf16*)alloc((size_t)TT * BB * DD * 2 * 2);
  bf16*  w0c   = (bf16*)alloc((size_t)NG4 * DD * 2 * 2);
  bf16*  w1c   = (bf16*)alloc((size_t)NG4 * HH * 2 * 2);
  bf16*  wpk0h = (bf16*)alloc((size_t)NG4 * HH * 2);
  bf16*  wpk0l = (bf16*)alloc((size_t)NG4 * HH * 2);
  bf16*  wpk1h = (bf16*)alloc((size_t)NG4 * HH * 2);
  bf16*  wpk1l = (bf16*)alloc((size_t)NG4 * HH * 2);
  bf16*  svc0  = (bf16*)alloc((size_t)(ct + 1) * SLOTB);  // layer-0 h chain
  bf16*  svc1  = (bf16*)alloc((size_t)(ct + 1) * SLOTB);  // layer-1 h chain
  float* xgT0  = (float*)alloc((size_t)ct * BB * NG4 * 4);
  float* xgT1  = (float*)alloc((size_t)ct * BB * NG4 * 4);
  float* c0    = (float*)alloc((size_t)BB * HH * 4);
  float* c1    = (float*)alloc((size_t)BB * HH * 4);
  int*   flagsA = (int*)alloc((size_t)NWG * 4);
  int*   flagsB = (int*)alloc((size_t)NWG * 4);

  cast_interleave<<<(TT * BB * DD / 8 + 255) / 256, 256, 0, stream>>>(x, xc, TT * BB * DD / 8);
  cast_interleave<<<(NG4 * DD / 8 + 255) / 256, 256, 0, stream>>>(wih0, w0c, NG4 * DD / 8);
  cast_interleave<<<(NG4 * HH / 8 + 255) / 256, 256, 0, stream>>>(wih1, w1c, NG4 * HH / 8);
  pack_whh_frag<<<2048, 256, 0, stream>>>(whh0, wpk0h, wpk0l);
  pack_whh_frag<<<2048, 256, 0, stream>>>(whh1, wpk1h, wpk1l);

  hipMemsetAsync(svc0, 0, SLOTB, stream);             // h0 initial state (slot 0)
  hipMemsetAsync(svc1, 0, SLOTB, stream);             // h1 initial state (slot 0)
  hipMemsetAsync(c0, 0, (size_t)BB * HH * 4, stream);
  hipMemsetAsync(c1, 0, (size_t)BB * HH * 4, stream);
  hipMemsetAsync(flagsA, 0, (size_t)NWG * 4, stream); // once; values monotonic after
  hipMemsetAsync(flagsB, 0, (size_t)NWG * 4, stream);

  const int gemmGrid = (ct * BB / BM) * (NG4 / BN);   // 1024 at ct=64
  int fb0 = 0, fb1 = 0;

  ScanArgs a0 = {wpk0h, wpk0l, xgT0, svc0, c0, flagsB, (float*)nullptr, 0};  // layer-0
  ScanArgs a1 = {wpk1h, wpk1l, xgT1, svc1, c1, flagsA, (float*)nullptr, 0};  // layer-1

  // prologue: layer-0 projection chunk 0 + solo scan
  GemmArgs g0c0 = {xc, w0c, bih0, bhh0, xgT0, DD, 0};
  gemm_dual<<<gemmGrid, 256, 0, stream>>>(g0c0, g0c0, gemmGrid);
  a0.fbase = fb0;
  lstm_scan<<<NWG, 512, 0, stream>>>(a0, a0, NWG, ct);
  fb0 += ct;

  for (int c = 0; c < nch; ++c) {
    GemmArgs g1 = {svc0 + SLOT, w1c, bih1, bhh1, xgT1, HH, 1};   // layer-1 proj c
    a1.outp = out + (size_t)c * ct * BB * HH;
    if (c + 1 < nch) {
      GemmArgs g0n = {xc + (size_t)(c + 1) * ct * BB * DD * 2,
                      w0c, bih0, bhh0, xgT0, DD, 0};             // layer-0 proj c+1
      gemm_dual<<<2 * gemmGrid, 256, 0, stream>>>(g1, g0n, gemmGrid);
      a1.fbase = fb1;
      a0.fbase = fb0;
      // fused: WGs 0..127 = layer-1 chunk c ; WGs 128..255 = layer-0 chunk c+1
      lstm_scan<<<2 * NWG, 512, 0, stream>>>(a1, a0, NWG, ct);
      fb1 += ct; fb0 += ct;
    } else {
      gemm_dual<<<gemmGrid, 256, 0, stream>>>(g1, g1, gemmGrid);
      a1.fbase = fb1;
      lstm_scan<<<NWG, 512, 0, stream>>>(a1, a1, NWG, ct);
      fb1 += ct;
    }
  }
}

// Round 14
// 5831.097 us; speedup vs baseline: 1.5030x; 1.3593x over previous
//
#include <hip/hip_runtime.h>
#include <hip/hip_bf16.h>

#define TT 512
#define BB 64
#define DD 1024
#define HH 1024
#define NG4 4096
#define NWG 128
#define FSTRIDE 32        // ints per flag slot (128B = one L2 line)
#define SLOT 131072       // bf16 elems per h slot (4 blocks x 32768)
#define SLOTB 262144      // bytes per h slot

typedef short bf16x8 __attribute__((ext_vector_type(8)));
typedef float f32x4 __attribute__((ext_vector_type(4)));
typedef __hip_bfloat16 bf16;

static __device__ __forceinline__ unsigned short bfbits(float f) {
  bf16 h = __float2bfloat16(f);
  return *reinterpret_cast<unsigned short*>(&h);
}
static __device__ __forceinline__ float bf2f(unsigned short u) {
  bf16 h = *reinterpret_cast<bf16*>(&u);
  return __bfloat162float(h);
}
static __device__ __forceinline__ void st_agent4(void* p, unsigned v) {
  __hip_atomic_store((unsigned*)p, v, __ATOMIC_RELAXED, __HIP_MEMORY_SCOPE_AGENT);
}
// async global->LDS, 16B per lane; dest must be lane-linear (base + lane*16)
static __device__ __forceinline__ void gload_lds16(const bf16* g, bf16* l) {
  __builtin_amdgcn_global_load_lds(
      (const __attribute__((address_space(1))) void*)g,
      (__attribute__((address_space(3))) void*)l, 16, 0, 0);
}

// ---- cast fp32 -> interleaved hi|lo groups: out[g*16..+8)=hi8, [+8..+16)=lo8 ----
__global__ __launch_bounds__(256) void cast_interleave(const float* __restrict__ in,
                                                       bf16* __restrict__ out,
                                                       int ngroups) {
  int g = blockIdx.x * 256 + threadIdx.x;
  if (g >= ngroups) return;
  float4 v0 = *reinterpret_cast<const float4*>(in + (size_t)g * 8);
  float4 v1 = *reinterpret_cast<const float4*>(in + (size_t)g * 8 + 4);
  float f[8] = {v0.x, v0.y, v0.z, v0.w, v1.x, v1.y, v1.z, v1.w};
  short ho[8], lo[8];
#pragma unroll
  for (int j = 0; j < 8; ++j) {
    unsigned short hb = bfbits(f[j]);
    ho[j] = (short)hb;
    lo[j] = (short)bfbits(f[j] - bf2f(hb));
  }
  *reinterpret_cast<bf16x8*>(out + (size_t)g * 16)     = *reinterpret_cast<bf16x8*>(ho);
  *reinterpret_cast<bf16x8*>(out + (size_t)g * 16 + 8) = *reinterpret_cast<bf16x8*>(lo);
}

// ---- pack w_hh into per-WG fragment-major hi/lo --------------------------------
__global__ __launch_bounds__(256) void pack_whh_frag(const float* __restrict__ w,
                                                     bf16* __restrict__ ph,
                                                     bf16* __restrict__ pl) {
  int gid = blockIdx.x * 256 + threadIdx.x;   // 128*4096 groups
  int us  = gid >> 12;
  int rem = gid & 4095;
  int kcg = rem >> 7, n = (rem >> 6) & 1, l = rem & 63;
  int p = n * 16 + (l & 15);
  int q = p & 3, u = p >> 2;
  int k = kcg * 32 + (l >> 4) * 8;
  size_t src = (size_t)(q * 1024 + us * 8 + u) * HH + k;
  float4 v0 = *reinterpret_cast<const float4*>(w + src);
  float4 v1 = *reinterpret_cast<const float4*>(w + src + 4);
  float f[8] = {v0.x, v0.y, v0.z, v0.w, v1.x, v1.y, v1.z, v1.w};
  short ho[8], lo[8];
#pragma unroll
  for (int j = 0; j < 8; ++j) {
    unsigned short hb = bfbits(f[j]);
    ho[j] = (short)hb;
    lo[j] = (short)bfbits(f[j] - bf2f(hb));
  }
  *reinterpret_cast<bf16x8*>(ph + (size_t)gid * 8) = *reinterpret_cast<bf16x8*>(ho);
  *reinterpret_cast<bf16x8*>(pl + (size_t)gid * 8) = *reinterpret_cast<bf16x8*>(lo);
}

// ---- 3-term split-bf16 MFMA GEMM body, M=N=4096 fixed --------------------------
#define BM 128
#define BN 128
#define BKK 64

struct GemmArgs {
  const bf16* A; const bf16* B;
  const float* bias1; const float* bias2;
  float* C; int K; int alay;
};

template <int ALAY>
static __device__ __forceinline__ void gemm3_body(const GemmArgs G, bf16* smem,
                                                  int bidx, int nwg) {
  bf16 (*sAh)[BKK] = reinterpret_cast<bf16(*)[BKK]>(smem);
  bf16 (*sAl)[BKK] = reinterpret_cast<bf16(*)[BKK]>(smem + 8192);
  bf16 (*sBh)[BKK] = reinterpret_cast<bf16(*)[BKK]>(smem + 16384);
  bf16 (*sBl)[BKK] = reinterpret_cast<bf16(*)[BKK]>(smem + 24576);
  const int tid  = threadIdx.x;
  const int lane = tid & 63;
  const int wv   = tid >> 6;
  const int wr   = wv >> 1, wc = wv & 1;
  const int nbx  = 4096 / BN;
  // XCD-aware bijective swizzle (nwg % 8 == 0 by construction)
  const int swz  = (bidx & 7) * (nwg >> 3) + (bidx >> 3);
  const int bx   = swz % nbx, by = swz / nbx;
  const int l15  = lane & 15, l4 = lane >> 4;
  const int K    = G.K;
  const int K8   = K >> 3;

  f32x4 acc[4][4] = {};

  for (int k0 = 0; k0 < K; k0 += BKK) {
    __syncthreads();
#pragma unroll
    for (int i = 0; i < 4; ++i) {
      int f  = i * 256 + tid;
      int r  = f >> 3;
      int k8 = f & 7;
      bf16* dAh = smem + (size_t)f * 8;
      bf16* dAl = smem + 8192 + (size_t)f * 8;
      bf16* dBh = smem + 16384 + (size_t)f * 8;
      bf16* dBl = smem + 24576 + (size_t)f * 8;
      if constexpr (ALAY == 0) {
        const bf16* gA = G.A + ((size_t)(by * BM + r) * K8 + (k0 >> 3) + k8) * 16;
        gload_lds16(gA, dAh);
        gload_lds16(gA + 8, dAl);
      } else {
        int gr = by * BM + r;
        int t  = gr >> 6, b = gr & 63;
        int k8g = (k0 >> 3) + k8;
        int kcg = k8g >> 2, s4 = k8g & 3;
        const bf16* gA = G.A + (size_t)t * SLOT + (size_t)(b >> 4) * 32768
                       + (size_t)kcg * 1024 + (size_t)(s4 * 16 + (b & 15)) * 8;
        gload_lds16(gA, dAh);
        gload_lds16(gA + 512, dAl);
      }
      const bf16* gB = G.B + ((size_t)(bx * BN + r) * K8 + (k0 >> 3) + k8) * 16;
      gload_lds16(gB, dBh);
      gload_lds16(gB + 8, dBl);
    }
    __syncthreads();   // compiler drains vmcnt(0) for the lds-loads here
#pragma unroll
    for (int kk = 0; kk < BKK; kk += 32) {
      const int kf = kk + (l4 << 3);
      bf16x8 a_h[4], a_l[4], b_h[4], b_l[4];
#pragma unroll
      for (int m = 0; m < 4; ++m) {
        a_h[m] = *reinterpret_cast<const bf16x8*>(&sAh[wr * 64 + m * 16 + l15][kf]);
        a_l[m] = *reinterpret_cast<const bf16x8*>(&sAl[wr * 64 + m * 16 + l15][kf]);
      }
#pragma unroll
      for (int n = 0; n < 4; ++n) {
        b_h[n] = *reinterpret_cast<const bf16x8*>(&sBh[wc * 64 + n * 16 + l15][kf]);
        b_l[n] = *reinterpret_cast<const bf16x8*>(&sBl[wc * 64 + n * 16 + l15][kf]);
      }
#pragma unroll
      for (int m = 0; m < 4; ++m)
#pragma unroll
        for (int n = 0; n < 4; ++n) {
          acc[m][n] = __builtin_amdgcn_mfma_f32_16x16x32_bf16(a_h[m], b_h[n], acc[m][n], 0, 0, 0);
          acc[m][n] = __builtin_amdgcn_mfma_f32_16x16x32_bf16(a_l[m], b_h[n], acc[m][n], 0, 0, 0);
          acc[m][n] = __builtin_amdgcn_mfma_f32_16x16x32_bf16(a_h[m], b_l[n], acc[m][n], 0, 0, 0);
        }
    }
  }
#pragma unroll
  for (int n = 0; n < 4; ++n) {
    int col = bx * BN + wc * 64 + n * 16 + l15;
    float bv = G.bias1[col] + G.bias2[col];
#pragma unroll
    for (int m = 0; m < 4; ++m) {
      int row0 = by * BM + wr * 64 + m * 16 + l4 * 4;
      int t = row0 >> 6, b0 = row0 & 63;
      float4 v;
      v.x = acc[m][n][0] + bv;
      v.y = acc[m][n][1] + bv;
      v.z = acc[m][n][2] + bv;
      v.w = acc[m][n][3] + bv;
      *reinterpret_cast<float4*>(G.C + (size_t)t * (NG4 * 64) + (size_t)col * 64 + b0) = v;
    }
  }
}

// dual-role GEMM: blocks [0,g0) run GA, [g0,grid) run GB
__global__ __launch_bounds__(256) void gemm_dual(GemmArgs GA, GemmArgs GB, int g0) {
  __shared__ bf16 smem[32768];
  const int b = (int)blockIdx.x;
  if (b < g0) {
    if (GA.alay) gemm3_body<1>(GA, smem, b, g0);
    else         gemm3_body<0>(GA, smem, b, g0);
  } else {
    if (GB.alay) gemm3_body<1>(GB, smem, b - g0, (int)gridDim.x - g0);
    else         gemm3_body<0>(GB, smem, b - g0, (int)gridDim.x - g0);
  }
}

// ---- scan parameter set (one layer-chunk) --------------------------------------
struct ScanArgs {
  const bf16* wpkh; const bf16* wpkl;   // [128][32768] packed recurrent weights
  const float* xgT;                     // [CT][4096][64]
  bf16* hbase;                          // chain: CT+1 slots (slot s read at step s)
  float* cst;                           // [64][1024]
  int* flags;                           // [NWG*FSTRIDE], one 128B line per WG
  float* outp;                          // [CT*64][1024] or null
  int fbase;                            // cumulative steps already signaled
};

// ---- persistent chunk scan, dual-role, centralized barrier, padded flags -------
__global__ __launch_bounds__(512, 1) void lstm_scan(ScanArgs PA, ScanArgs PB,
                                                    int nwg0, int CT) {
  __shared__ bf16  sW[65536];        // hi at [0,32768), lo at [32768,65536)
  __shared__ float gred[4][16][33];

  const int role = (blockIdx.x >= nwg0) ? 1 : 0;
  const ScanArgs P = role ? PB : PA;
  const int wg   = blockIdx.x - (role ? nwg0 : 0);

  const int tid  = threadIdx.x;
  const int lane = tid & 63;
  const int wv   = tid >> 6;
  const int m    = wv >> 1;
  const int kh   = wv & 1;
  const int j0   = wg * 8;
  const int l15  = lane & 15, l4 = lane >> 4;

  // stage weights into LDS once
  {
    const bf16x8* srcH = reinterpret_cast<const bf16x8*>(P.wpkh + (size_t)wg * 32768);
    const bf16x8* srcL = reinterpret_cast<const bf16x8*>(P.wpkl + (size_t)wg * 32768);
    bf16x8* dH = reinterpret_cast<bf16x8*>(sW);
    bf16x8* dL = reinterpret_cast<bf16x8*>(sW + 32768);
    for (int i = tid; i < 4096; i += 512) { dH[i] = srcH[i]; dL[i] = srcL[i]; }
  }

  // pointwise ownership (kh==0 waves): batch = m*16+bl, units j0+2*up, +1
  const int bl = lane & 15;
  const int up = lane >> 4;
  const int pbatch = m * 16 + bl;
  float cS0 = 0.f, cS1 = 0.f;
  if (kh == 0) {
    cS0 = P.cst[(size_t)pbatch * HH + j0 + 2 * up];
    cS1 = P.cst[(size_t)pbatch * HH + j0 + 2 * up + 1];
  }
  __syncthreads();

  for (int s = 0; s < CT; ++s) {
    const bf16* hrd = P.hbase + (size_t)s * SLOT;
    bf16*       hwr = P.hbase + (size_t)(s + 1) * SLOT;

    // xq prefetch (kh==0 waves), normal cached loads
    float xq[2][4];
    const float* xgs = P.xgT + (size_t)s * (NG4 * 64);
    if (kh == 0) {
#pragma unroll
      for (int d = 0; d < 2; ++d) {
        int j = j0 + 2 * up + d;
#pragma unroll
        for (int q = 0; q < 4; ++q)
          xq[d][q] = xgs[(size_t)(q * 1024 + j) * 64 + pbatch];
      }
    }

    // dense h loads (cached; L2 shared across the XCD's WGs)
    const bf16* hp = hrd + (size_t)m * 32768 + (size_t)(kh * 16) * 1024 + (size_t)lane * 8;

    f32x4 acc0 = {}, acc1 = {};
#pragma unroll
    for (int T = 0; T < 16; ++T) {
      const int kcg_ = kh * 16 + T;
      bf16x8 hh = *reinterpret_cast<const bf16x8*>(hp + T * 1024);
      bf16x8 hl = *reinterpret_cast<const bf16x8*>(hp + T * 1024 + 512);
      bf16x8 bh0 = *reinterpret_cast<const bf16x8*>(sW + ((kcg_ * 2 + 0) * 64 + lane) * 8);
      bf16x8 bw0 = *reinterpret_cast<const bf16x8*>(sW + 32768 + ((kcg_ * 2 + 0) * 64 + lane) * 8);
      bf16x8 bh1 = *reinterpret_cast<const bf16x8*>(sW + ((kcg_ * 2 + 1) * 64 + lane) * 8);
      bf16x8 bw1 = *reinterpret_cast<const bf16x8*>(sW + 32768 + ((kcg_ * 2 + 1) * 64 + lane) * 8);
      acc0 = __builtin_amdgcn_mfma_f32_16x16x32_bf16(hh, bh0, acc0, 0, 0, 0);
      acc0 = __builtin_amdgcn_mfma_f32_16x16x32_bf16(hl, bh0, acc0, 0, 0, 0);
      acc0 = __builtin_amdgcn_mfma_f32_16x16x32_bf16(hh, bw0, acc0, 0, 0, 0);
      acc1 = __builtin_amdgcn_mfma_f32_16x16x32_bf16(hh, bh1, acc1, 0, 0, 0);
      acc1 = __builtin_amdgcn_mfma_f32_16x16x32_bf16(hl, bh1, acc1, 0, 0, 0);
      acc1 = __builtin_amdgcn_mfma_f32_16x16x32_bf16(hh, bw1, acc1, 0, 0, 0);
    }

    // one-round reduction: kh==1 waves store partials, kh==0 add
    if (kh == 1) {
#pragma unroll
      for (int r = 0; r < 4; ++r) {
        gred[m][l4 * 4 + r][l15]      = acc0[r];
        gred[m][l4 * 4 + r][16 + l15] = acc1[r];
      }
    }
    __syncthreads();
    if (kh == 0) {
#pragma unroll
      for (int r = 0; r < 4; ++r) {
        int rr = l4 * 4 + r;
        acc0[r] += gred[m][rr][l15];
        acc1[r] += gred[m][rr][16 + l15];
        gred[m][rr][l15]      = acc0[r];
        gred[m][rr][16 + l15] = acc1[r];
      }
      asm volatile("s_waitcnt lgkmcnt(0)" ::: "memory");

      float hv[2];
#pragma unroll
      for (int d = 0; d < 2; ++d) {
        int uu = 2 * up + d;
        float iv = gred[m][bl][uu * 4 + 0] + xq[d][0];
        float fv = gred[m][bl][uu * 4 + 1] + xq[d][1];
        float gv = gred[m][bl][uu * 4 + 2] + xq[d][2];
        float ov = gred[m][bl][uu * 4 + 3] + xq[d][3];
        iv = 1.f / (1.f + __expf(-iv));
        fv = 1.f / (1.f + __expf(-fv));
        gv = tanhf(gv);
        ov = 1.f / (1.f + __expf(-ov));
        float cv = fv * (d ? cS1 : cS0) + iv * gv;
        if (d) cS1 = cv; else cS0 = cv;
        hv[d] = ov * tanhf(cv);
      }
      unsigned short h0b = bfbits(hv[0]), h1b = bfbits(hv[1]);
      unsigned short l0b = bfbits(hv[0] - bf2f(h0b));
      unsigned short l1b = bfbits(hv[1] - bf2f(h1b));
      unsigned hiW = (unsigned)h0b | ((unsigned)h1b << 16);
      unsigned loW = (unsigned)l0b | ((unsigned)l1b << 16);
      // dense store: kcg = wg>>2, lane' = (wg&3)*16+bl, elems 2up(+1); lo at +512
      size_t wo = (size_t)m * 32768 + (size_t)(wg >> 2) * 1024
                + (size_t)((wg & 3) * 16 + bl) * 8 + 2 * up;
      st_agent4(hwr + wo, hiW);
      st_agent4(hwr + wo + 512, loW);
      if (s == CT - 1) {           // seed slot 0 for the next chunk (carry)
        st_agent4(P.hbase + wo, hiW);
        st_agent4(P.hbase + wo + 512, loW);
      }
      if (P.outp) {
        float2 o2 = make_float2(hv[0], hv[1]);
        *reinterpret_cast<float2*>(P.outp + (size_t)(s * 64 + pbatch) * HH + j0 + 2 * up) = o2;
      }
    }

    // per-role grid barrier (skip after last step): monotonic padded flags
    if (s + 1 < CT) {
      __syncthreads();   // drains vmcnt: h stores at coherent point before signal
      if (tid == 0)
        __hip_atomic_store(&P.flags[wg * FSTRIDE], P.fbase + s + 1,
                           __ATOMIC_RELAXED, __HIP_MEMORY_SCOPE_AGENT);
      if (tid < NWG) {
        while (__hip_atomic_load(&P.flags[tid * FSTRIDE], __ATOMIC_RELAXED,
                                 __HIP_MEMORY_SCOPE_AGENT) < P.fbase + s + 1)
          __builtin_amdgcn_s_sleep(1);
      }
      __syncthreads();   // compiler+HW barrier: h loads can't hoist above the poll
    }
  }

  if (kh == 0) {
    P.cst[(size_t)pbatch * HH + j0 + 2 * up]     = cS0;
    P.cst[(size_t)pbatch * HH + j0 + 2 * up + 1] = cS1;
  }
}

extern "C" void kernel_launch(void* const* d_in, const int* in_sizes, int n_in,
                              void* d_out, int out_size, void* d_ws, size_t ws_size,
                              hipStream_t stream) {
  const float* x    = (const float*)d_in[0];
  const float* wih0 = (const float*)d_in[1];
  const float* whh0 = (const float*)d_in[2];
  const float* bih0 = (const float*)d_in[3];
  const float* bhh0 = (const float*)d_in[4];
  const float* wih1 = (const float*)d_in[5];
  const float* whh1 = (const float*)d_in[6];
  const float* bih1 = (const float*)d_in[7];
  const float* bhh1 = (const float*)d_in[8];
  float* out = (float*)d_out;

  int ct = 64;
  for (;;) {
    size_t fixed = (size_t)TT * BB * DD * 2 * 2        // xc interleaved
                 + (size_t)NG4 * DD * 2 * 2            // w0c interleaved
                 + (size_t)NG4 * HH * 2 * 2            // w1c interleaved
                 + (size_t)NG4 * HH * 2 * 2 * 2        // packed whh hi/lo x2 layers
                 + (size_t)2 * BB * HH * 4             // c states
                 + ((size_t)1 << 18);
    size_t var = (size_t)2 * ct * BB * NG4 * 4         // xgT x2
               + (size_t)2 * (ct + 1) * SLOTB;         // two h chains
    if (fixed + var <= ws_size || ct == 8) break;
    ct >>= 1;
  }
  const int nch = TT / ct;

  char* ws = (char*)d_ws;
  size_t off = 0;
  auto alloc = [&](size_t bytes) -> char* {
    char* p = ws + off;
    off += (bytes + 255) & ~(size_t)255;
    return p;
  };
  bf16*  xc    = (bf16*)alloc((size_t)TT * BB * DD * 2 * 2);
  bf16*  w0c   = (bf16*)alloc((size_t)NG4 * DD * 2 * 2);
  bf16*  w1c   = (bf16*)alloc((size_t)NG4 * HH * 2 * 2);
  bf16*  wpk0h = (bf16*)alloc((size_t)NG4 * HH * 2);
  bf16*  wpk0l = (bf16*)alloc((size_t)NG4 * HH * 2);
  bf16*  wpk1h = (bf16*)alloc((size_t)NG4 * HH * 2);
  bf16*  wpk1l = (bf16*)alloc((size_t)NG4 * HH * 2);
  bf16*  svc0  = (bf16*)alloc((size_t)(ct + 1) * SLOTB);  // layer-0 h chain
  bf16*  svc1  = (bf16*)alloc((size_t)(ct + 1) * SLOTB);  // layer-1 h chain
  float* xgT0  = (float*)alloc((size_t)ct * BB * NG4 * 4);
  float* xgT1  = (float*)alloc((size_t)ct * BB * NG4 * 4);
  float* c0    = (float*)alloc((size_t)BB * HH * 4);
  float* c1    = (float*)alloc((size_t)BB * HH * 4);
  int*   flagsA = (int*)alloc((size_t)NWG * FSTRIDE * 4);
  int*   flagsB = (int*)alloc((size_t)NWG * FSTRIDE * 4);

  cast_interleave<<<(TT * BB * DD / 8 + 255) / 256, 256, 0, stream>>>(x, xc, TT * BB * DD / 8);
  cast_interleave<<<(NG4 * DD / 8 + 255) / 256, 256, 0, stream>>>(wih0, w0c, NG4 * DD / 8);
  cast_interleave<<<(NG4 * HH / 8 + 255) / 256, 256, 0, stream>>>(wih1, w1c, NG4 * HH / 8);
  pack_whh_frag<<<2048, 256, 0, stream>>>(whh0, wpk0h, wpk0l);
  pack_whh_frag<<<2048, 256, 0, stream>>>(whh1, wpk1h, wpk1l);

  hipMemsetAsync(svc0, 0, SLOTB, stream);             // h0 initial state (slot 0)
  hipMemsetAsync(svc1, 0, SLOTB, stream);             // h1 initial state (slot 0)
  hipMemsetAsync(c0, 0, (size_t)BB * HH * 4, stream);
  hipMemsetAsync(c1, 0, (size_t)BB * HH * 4, stream);
  hipMemsetAsync(flagsA, 0, (size_t)NWG * FSTRIDE * 4, stream); // once; monotonic
  hipMemsetAsync(flagsB, 0, (size_t)NWG * FSTRIDE * 4, stream);

  const int gemmGrid = (ct * BB / BM) * (NG4 / BN);   // 1024 at ct=64
  int fb0 = 0, fb1 = 0;

  ScanArgs a0 = {wpk0h, wpk0l, xgT0, svc0, c0, flagsB, (float*)nullptr, 0};  // layer-0
  ScanArgs a1 = {wpk1h, wpk1l, xgT1, svc1, c1, flagsA, (float*)nullptr, 0};  // layer-1

  // prologue: layer-0 projection chunk 0 + solo scan
  GemmArgs g0c0 = {xc, w0c, bih0, bhh0, xgT0, DD, 0};
  gemm_dual<<<gemmGrid, 256, 0, stream>>>(g0c0, g0c0, gemmGrid);
  a0.fbase = fb0;
  lstm_scan<<<NWG, 512, 0, stream>>>(a0, a0, NWG, ct);
  fb0 += ct;

  for (int c = 0; c < nch; ++c) {
    GemmArgs g1 = {svc0 + SLOT, w1c, bih1, bhh1, xgT1, HH, 1};   // layer-1 proj c
    a1.outp = out + (size_t)c * ct * BB * HH;
    if (c + 1 < nch) {
      GemmArgs g0n = {xc + (size_t)(c + 1) * ct * BB * DD * 2,
                      w0c, bih0, bhh0, xgT0, DD, 0};             // layer-0 proj c+1
      gemm_dual<<<2 * gemmGrid, 256, 0, stream>>>(g1, g0n, gemmGrid);
      a1.fbase = fb1;
      a0.fbase = fb0;
      // fused: WGs 0..127 = layer-1 chunk c ; WGs 128..255 = layer-0 chunk c+1
      lstm_scan<<<2 * NWG, 512, 0, stream>>>(a1, a0, NWG, ct);
      fb1 += ct; fb0 += ct;
    } else {
      gemm_dual<<<gemmGrid, 256, 0, stream>>>(g1, g1, gemmGrid);
      a1.fbase = fb1;
      lstm_scan<<<NWG, 512, 0, stream>>>(a1, a1, NWG, ct);
      fb1 += ct;
    }
  }
}

// Round 17
// 5813.342 us; speedup vs baseline: 1.5076x; 1.0031x over previous
//
#include <hip/hip_runtime.h>
#include <hip/hip_bf16.h>

#define TT 512
#define BB 64
#define DD 1024
#define HH 1024
#define NG4 4096
#define NWG 128
#define FSTRIDE 32        // ints per flag slot (128B = one L2 line)
#define SLOT 131072       // bf16 elems per h slot (4 blocks x 32768)
#define SLOTB 262144      // bytes per h slot

typedef short bf16x8 __attribute__((ext_vector_type(8)));
typedef float f32x4 __attribute__((ext_vector_type(4)));
typedef __hip_bfloat16 bf16;

static __device__ __forceinline__ unsigned short bfbits(float f) {
  bf16 h = __float2bfloat16(f);
  return *reinterpret_cast<unsigned short*>(&h);
}
static __device__ __forceinline__ float bf2f(unsigned short u) {
  bf16 h = *reinterpret_cast<bf16*>(&u);
  return __bfloat162float(h);
}
static __device__ __forceinline__ void st_agent4(void* p, unsigned v) {
  __hip_atomic_store((unsigned*)p, v, __ATOMIC_RELAXED, __HIP_MEMORY_SCOPE_AGENT);
}
// async global->LDS, 16B per lane; dest must be lane-linear (base + lane*16)
static __device__ __forceinline__ void gload_lds16(const bf16* g, bf16* l) {
  __builtin_amdgcn_global_load_lds(
      (const __attribute__((address_space(1))) void*)g,
      (__attribute__((address_space(3))) void*)l, 16, 0, 0);
}

// ---- cast fp32 -> interleaved hi|lo groups: out[g*16..+8)=hi8, [+8..+16)=lo8 ----
__global__ __launch_bounds__(256) void cast_interleave(const float* __restrict__ in,
                                                       bf16* __restrict__ out,
                                                       int ngroups) {
  int g = blockIdx.x * 256 + threadIdx.x;
  if (g >= ngroups) return;
  float4 v0 = *reinterpret_cast<const float4*>(in + (size_t)g * 8);
  float4 v1 = *reinterpret_cast<const float4*>(in + (size_t)g * 8 + 4);
  float f[8] = {v0.x, v0.y, v0.z, v0.w, v1.x, v1.y, v1.z, v1.w};
  short ho[8], lo[8];
#pragma unroll
  for (int j = 0; j < 8; ++j) {
    unsigned short hb = bfbits(f[j]);
    ho[j] = (short)hb;
    lo[j] = (short)bfbits(f[j] - bf2f(hb));
  }
  *reinterpret_cast<bf16x8*>(out + (size_t)g * 16)     = *reinterpret_cast<bf16x8*>(ho);
  *reinterpret_cast<bf16x8*>(out + (size_t)g * 16 + 8) = *reinterpret_cast<bf16x8*>(lo);
}

// ---- pack w_hh into per-WG fragment-major hi/lo --------------------------------
__global__ __launch_bounds__(256) void pack_whh_frag(const float* __restrict__ w,
                                                     bf16* __restrict__ ph,
                                                     bf16* __restrict__ pl) {
  int gid = blockIdx.x * 256 + threadIdx.x;   // 128*4096 groups
  int us  = gid >> 12;
  int rem = gid & 4095;
  int kcg = rem >> 7, n = (rem >> 6) & 1, l = rem & 63;
  int p = n * 16 + (l & 15);
  int q = p & 3, u = p >> 2;
  int k = kcg * 32 + (l >> 4) * 8;
  size_t src = (size_t)(q * 1024 + us * 8 + u) * HH + k;
  float4 v0 = *reinterpret_cast<const float4*>(w + src);
  float4 v1 = *reinterpret_cast<const float4*>(w + src + 4);
  float f[8] = {v0.x, v0.y, v0.z, v0.w, v1.x, v1.y, v1.z, v1.w};
  short ho[8], lo[8];
#pragma unroll
  for (int j = 0; j < 8; ++j) {
    unsigned short hb = bfbits(f[j]);
    ho[j] = (short)hb;
    lo[j] = (short)bfbits(f[j] - bf2f(hb));
  }
  *reinterpret_cast<bf16x8*>(ph + (size_t)gid * 8) = *reinterpret_cast<bf16x8*>(ho);
  *reinterpret_cast<bf16x8*>(pl + (size_t)gid * 8) = *reinterpret_cast<bf16x8*>(lo);
}

// ---- 3-term split-bf16 MFMA GEMM body, M=N=4096 fixed --------------------------
#define BM 128
#define BN 128
#define BKK 64

struct GemmArgs {
  const bf16* A; const bf16* B;
  const float* bias1; const float* bias2;
  float* C; int K; int alay;
};

template <int ALAY>
static __device__ __forceinline__ void gemm3_body(const GemmArgs G, bf16* smem,
                                                  int bidx, int nwg) {
  bf16 (*sAh)[BKK] = reinterpret_cast<bf16(*)[BKK]>(smem);
  bf16 (*sAl)[BKK] = reinterpret_cast<bf16(*)[BKK]>(smem + 8192);
  bf16 (*sBh)[BKK] = reinterpret_cast<bf16(*)[BKK]>(smem + 16384);
  bf16 (*sBl)[BKK] = reinterpret_cast<bf16(*)[BKK]>(smem + 24576);
  const int tid  = threadIdx.x;
  const int lane = tid & 63;
  const int wv   = tid >> 6;
  const int wr   = wv >> 1, wc = wv & 1;
  const int nbx  = 4096 / BN;
  // XCD-aware bijective swizzle (nwg % 8 == 0 by construction)
  const int swz  = (bidx & 7) * (nwg >> 3) + (bidx >> 3);
  const int bx   = swz % nbx, by = swz / nbx;
  const int l15  = lane & 15, l4 = lane >> 4;
  const int K    = G.K;
  const int K8   = K >> 3;

  f32x4 acc[4][4] = {};

  for (int k0 = 0; k0 < K; k0 += BKK) {
    __syncthreads();
#pragma unroll
    for (int i = 0; i < 4; ++i) {
      int f  = i * 256 + tid;
      int r  = f >> 3;
      int k8 = f & 7;
      bf16* dAh = smem + (size_t)f * 8;
      bf16* dAl = smem + 8192 + (size_t)f * 8;
      bf16* dBh = smem + 16384 + (size_t)f * 8;
      bf16* dBl = smem + 24576 + (size_t)f * 8;
      if constexpr (ALAY == 0) {
        const bf16* gA = G.A + ((size_t)(by * BM + r) * K8 + (k0 >> 3) + k8) * 16;
        gload_lds16(gA, dAh);
        gload_lds16(gA + 8, dAl);
      } else {
        int gr = by * BM + r;
        int t  = gr >> 6, b = gr & 63;
        int k8g = (k0 >> 3) + k8;
        int kcg = k8g >> 2, s4 = k8g & 3;
        const bf16* gA = G.A + (size_t)t * SLOT + (size_t)(b >> 4) * 32768
                       + (size_t)kcg * 1024 + (size_t)(s4 * 16 + (b & 15)) * 8;
        gload_lds16(gA, dAh);
        gload_lds16(gA + 512, dAl);
      }
      const bf16* gB = G.B + ((size_t)(bx * BN + r) * K8 + (k0 >> 3) + k8) * 16;
      gload_lds16(gB, dBh);
      gload_lds16(gB + 8, dBl);
    }
    __syncthreads();   // compiler drains vmcnt(0) for the lds-loads here
#pragma unroll
    for (int kk = 0; kk < BKK; kk += 32) {
      const int kf = kk + (l4 << 3);
      bf16x8 a_h[4], a_l[4], b_h[4], b_l[4];
#pragma unroll
      for (int m = 0; m < 4; ++m) {
        a_h[m] = *reinterpret_cast<const bf16x8*>(&sAh[wr * 64 + m * 16 + l15][kf]);
        a_l[m] = *reinterpret_cast<const bf16x8*>(&sAl[wr * 64 + m * 16 + l15][kf]);
      }
#pragma unroll
      for (int n = 0; n < 4; ++n) {
        b_h[n] = *reinterpret_cast<const bf16x8*>(&sBh[wc * 64 + n * 16 + l15][kf]);
        b_l[n] = *reinterpret_cast<const bf16x8*>(&sBl[wc * 64 + n * 16 + l15][kf]);
      }
#pragma unroll
      for (int m = 0; m < 4; ++m)
#pragma unroll
        for (int n = 0; n < 4; ++n) {
          acc[m][n] = __builtin_amdgcn_mfma_f32_16x16x32_bf16(a_h[m], b_h[n], acc[m][n], 0, 0, 0);
          acc[m][n] = __builtin_amdgcn_mfma_f32_16x16x32_bf16(a_l[m], b_h[n], acc[m][n], 0, 0, 0);
          acc[m][n] = __builtin_amdgcn_mfma_f32_16x16x32_bf16(a_h[m], b_l[n], acc[m][n], 0, 0, 0);
        }
    }
  }
#pragma unroll
  for (int n = 0; n < 4; ++n) {
    int col = bx * BN + wc * 64 + n * 16 + l15;
    float bv = G.bias1[col] + G.bias2[col];
#pragma unroll
    for (int m = 0; m < 4; ++m) {
      int row0 = by * BM + wr * 64 + m * 16 + l4 * 4;
      int t = row0 >> 6, b0 = row0 & 63;
      float4 v;
      v.x = acc[m][n][0] + bv;
      v.y = acc[m][n][1] + bv;
      v.z = acc[m][n][2] + bv;
      v.w = acc[m][n][3] + bv;
      *reinterpret_cast<float4*>(G.C + (size_t)t * (NG4 * 64) + (size_t)col * 64 + b0) = v;
    }
  }
}

// dual-role GEMM: blocks [0,g0) run GA, [g0,grid) run GB
__global__ __launch_bounds__(256) void gemm_dual(GemmArgs GA, GemmArgs GB, int g0) {
  __shared__ bf16 smem[32768];
  const int b = (int)blockIdx.x;
  if (b < g0) {
    if (GA.alay) gemm3_body<1>(GA, smem, b, g0);
    else         gemm3_body<0>(GA, smem, b, g0);
  } else {
    if (GB.alay) gemm3_body<1>(GB, smem, b - g0, (int)gridDim.x - g0);
    else         gemm3_body<0>(GB, smem, b - g0, (int)gridDim.x - g0);
  }
}

// ---- scan parameter set (one layer-chunk) --------------------------------------
struct ScanArgs {
  const bf16* wpkh; const bf16* wpkl;   // [128][32768] packed recurrent weights
  const float* xgT;                     // [CT][4096][64]
  bf16* hbase;                          // chain: CT+1 slots (slot s read at step s)
  float* cst;                           // [64][1024]
  int* flags;                           // [NWG*FSTRIDE], one 128B line per WG
  float* outp;                          // [CT*64][1024] or null
  int fbase;                            // cumulative steps already signaled
};

// ---- persistent chunk scan, dual-role, per-wave half-poll barrier --------------
// Wave (m,kh) reads h k-range [kh*512,(kh+1)*512) -> depends only on producer WGs
// [kh*64, kh*64+64). Barrier: drain-sync -> tid0 signal -> each wave's 64 lanes
// poll 1 producer flag of their half -> proceed (no joining syncthreads; the
// gred write for step s+1 by kh1 happens only after drain-sync(s), which kh0
// reaches only after its gred read for step s -> no WAR hazard).
__global__ __launch_bounds__(512, 1) void lstm_scan(ScanArgs PA, ScanArgs PB,
                                                    int nwg0, int CT) {
  __shared__ bf16  sW[65536];        // hi at [0,32768), lo at [32768,65536)
  __shared__ float gred[4][16][33];

  const int role = (blockIdx.x >= nwg0) ? 1 : 0;
  const ScanArgs P = role ? PB : PA;
  const int wg   = blockIdx.x - (role ? nwg0 : 0);

  const int tid  = threadIdx.x;
  const int lane = tid & 63;
  const int wv   = tid >> 6;
  const int m    = wv >> 1;
  const int kh   = wv & 1;
  const int j0   = wg * 8;
  const int l15  = lane & 15, l4 = lane >> 4;

  // stage weights into LDS once
  {
    const bf16x8* srcH = reinterpret_cast<const bf16x8*>(P.wpkh + (size_t)wg * 32768);
    const bf16x8* srcL = reinterpret_cast<const bf16x8*>(P.wpkl + (size_t)wg * 32768);
    bf16x8* dH = reinterpret_cast<bf16x8*>(sW);
    bf16x8* dL = reinterpret_cast<bf16x8*>(sW + 32768);
    for (int i = tid; i < 4096; i += 512) { dH[i] = srcH[i]; dL[i] = srcL[i]; }
  }

  // pointwise ownership (kh==0 waves): batch = m*16+bl, units j0+2*up, +1
  const int bl = lane & 15;
  const int up = lane >> 4;
  const int pbatch = m * 16 + bl;
  float cS0 = 0.f, cS1 = 0.f;
  if (kh == 0) {
    cS0 = P.cst[(size_t)pbatch * HH + j0 + 2 * up];
    cS1 = P.cst[(size_t)pbatch * HH + j0 + 2 * up + 1];
  }
  __syncthreads();

  for (int s = 0; s < CT; ++s) {
    const bf16* hrd = P.hbase + (size_t)s * SLOT;
    bf16*       hwr = P.hbase + (size_t)(s + 1) * SLOT;

    // xq prefetch (kh==0 waves), normal cached loads
    float xq[2][4];
    const float* xgs = P.xgT + (size_t)s * (NG4 * 64);
    if (kh == 0) {
#pragma unroll
      for (int d = 0; d < 2; ++d) {
        int j = j0 + 2 * up + d;
#pragma unroll
        for (int q = 0; q < 4; ++q)
          xq[d][q] = xgs[(size_t)(q * 1024 + j) * 64 + pbatch];
      }
    }

    // dense h loads (cached; L2 shared across the XCD's WGs)
    const bf16* hp = hrd + (size_t)m * 32768 + (size_t)(kh * 16) * 1024 + (size_t)lane * 8;

    f32x4 acc0 = {}, acc1 = {};
#pragma unroll
    for (int T = 0; T < 16; ++T) {
      const int kcg_ = kh * 16 + T;
      bf16x8 hh = *reinterpret_cast<const bf16x8*>(hp + T * 1024);
      bf16x8 hl = *reinterpret_cast<const bf16x8*>(hp + T * 1024 + 512);
      bf16x8 bh0 = *reinterpret_cast<const bf16x8*>(sW + ((kcg_ * 2 + 0) * 64 + lane) * 8);
      bf16x8 bw0 = *reinterpret_cast<const bf16x8*>(sW + 32768 + ((kcg_ * 2 + 0) * 64 + lane) * 8);
      bf16x8 bh1 = *reinterpret_cast<const bf16x8*>(sW + ((kcg_ * 2 + 1) * 64 + lane) * 8);
      bf16x8 bw1 = *reinterpret_cast<const bf16x8*>(sW + 32768 + ((kcg_ * 2 + 1) * 64 + lane) * 8);
      acc0 = __builtin_amdgcn_mfma_f32_16x16x32_bf16(hh, bh0, acc0, 0, 0, 0);
      acc0 = __builtin_amdgcn_mfma_f32_16x16x32_bf16(hl, bh0, acc0, 0, 0, 0);
      acc0 = __builtin_amdgcn_mfma_f32_16x16x32_bf16(hh, bw0, acc0, 0, 0, 0);
      acc1 = __builtin_amdgcn_mfma_f32_16x16x32_bf16(hh, bh1, acc1, 0, 0, 0);
      acc1 = __builtin_amdgcn_mfma_f32_16x16x32_bf16(hl, bh1, acc1, 0, 0, 0);
      acc1 = __builtin_amdgcn_mfma_f32_16x16x32_bf16(hh, bw1, acc1, 0, 0, 0);
    }

    // one-round reduction: kh==1 waves store partials, kh==0 add
    if (kh == 1) {
#pragma unroll
      for (int r = 0; r < 4; ++r) {
        gred[m][l4 * 4 + r][l15]      = acc0[r];
        gred[m][l4 * 4 + r][16 + l15] = acc1[r];
      }
    }
    __syncthreads();   // gred partials visible to kh0
    if (kh == 0) {
#pragma unroll
      for (int r = 0; r < 4; ++r) {
        int rr = l4 * 4 + r;
        acc0[r] += gred[m][rr][l15];
        acc1[r] += gred[m][rr][16 + l15];
        gred[m][rr][l15]      = acc0[r];
        gred[m][rr][16 + l15] = acc1[r];
      }
      asm volatile("s_waitcnt lgkmcnt(0)" ::: "memory");

      float hv[2];
#pragma unroll
      for (int d = 0; d < 2; ++d) {
        int uu = 2 * up + d;
        float iv = gred[m][bl][uu * 4 + 0] + xq[d][0];
        float fv = gred[m][bl][uu * 4 + 1] + xq[d][1];
        float gv = gred[m][bl][uu * 4 + 2] + xq[d][2];
        float ov = gred[m][bl][uu * 4 + 3] + xq[d][3];
        iv = 1.f / (1.f + __expf(-iv));
        fv = 1.f / (1.f + __expf(-fv));
        gv = tanhf(gv);
        ov = 1.f / (1.f + __expf(-ov));
        float cv = fv * (d ? cS1 : cS0) + iv * gv;
        if (d) cS1 = cv; else cS0 = cv;
        hv[d] = ov * tanhf(cv);
      }
      unsigned short h0b = bfbits(hv[0]), h1b = bfbits(hv[1]);
      unsigned short l0b = bfbits(hv[0] - bf2f(h0b));
      unsigned short l1b = bfbits(hv[1] - bf2f(h1b));
      unsigned hiW = (unsigned)h0b | ((unsigned)h1b << 16);
      unsigned loW = (unsigned)l0b | ((unsigned)l1b << 16);
      // dense store: kcg = wg>>2, lane' = (wg&3)*16+bl, elems 2up(+1); lo at +512
      size_t wo = (size_t)m * 32768 + (size_t)(wg >> 2) * 1024
                + (size_t)((wg & 3) * 16 + bl) * 8 + 2 * up;
      st_agent4(hwr + wo, hiW);
      st_agent4(hwr + wo + 512, loW);
      if (s == CT - 1) {           // seed slot 0 for the next chunk (carry)
        st_agent4(P.hbase + wo, hiW);
        st_agent4(P.hbase + wo + 512, loW);
      }
      if (P.outp) {
        float2 o2 = make_float2(hv[0], hv[1]);
        *reinterpret_cast<float2*>(P.outp + (size_t)(s * 64 + pbatch) * HH + j0 + 2 * up) = o2;
      }
    }

    // per-role barrier (skip after last step): drain-sync -> signal -> half-poll
    if (s + 1 < CT) {
      __syncthreads();   // drains vmcnt: all h stores at coherent point before signal
      if (tid == 0)
        __hip_atomic_store(&P.flags[wg * FSTRIDE], P.fbase + s + 1,
                           __ATOMIC_RELAXED, __HIP_MEMORY_SCOPE_AGENT);
      // per-wave poll: each lane watches one producer WG of this wave's k-half
      {
        const int tgt = P.fbase + s + 1;
        const int pwg = kh * 64 + lane;
        while (__hip_atomic_load(&P.flags[pwg * FSTRIDE], __ATOMIC_RELAXED,
                                 __HIP_MEMORY_SCOPE_AGENT) < tgt)
          __builtin_amdgcn_s_sleep(1);
      }
      asm volatile("" ::: "memory");        // no load hoisting above the poll
      __builtin_amdgcn_sched_barrier(0);
    }
  }

  if (kh == 0) {
    P.cst[(size_t)pbatch * HH + j0 + 2 * up]     = cS0;
    P.cst[(size_t)pbatch * HH + j0 + 2 * up + 1] = cS1;
  }
}

extern "C" void kernel_launch(void* const* d_in, const int* in_sizes, int n_in,
                              void* d_out, int out_size, void* d_ws, size_t ws_size,
                              hipStream_t stream) {
  const float* x    = (const float*)d_in[0];
  const float* wih0 = (const float*)d_in[1];
  const float* whh0 = (const float*)d_in[2];
  const float* bih0 = (const float*)d_in[3];
  const float* bhh0 = (const float*)d_in[4];
  const float* wih1 = (const float*)d_in[5];
  const float* whh1 = (const float*)d_in[6];
  const float* bih1 = (const float*)d_in[7];
  const float* bhh1 = (const float*)d_in[8];
  float* out = (float*)d_out;

  int ct = 64;
  for (;;) {
    size_t fixed = (size_t)TT * BB * DD * 2 * 2        // xc interleaved
                 + (size_t)NG4 * DD * 2 * 2            // w0c interleaved
                 + (size_t)NG4 * HH * 2 * 2            // w1c interleaved
                 + (size_t)NG4 * HH * 2 * 2 * 2        // packed whh hi/lo x2 layers
                 + (size_t)2 * BB * HH * 4             // c states
                 + ((size_t)1 << 18);
    size_t var = (size_t)2 * ct * BB * NG4 * 4         // xgT x2
               + (size_t)2 * (ct + 1) * SLOTB;         // two h chains
    if (fixed + var <= ws_size || ct == 8) break;
    ct >>= 1;
  }
  const int nch = TT / ct;

  char* ws = (char*)d_ws;
  size_t off = 0;
  auto alloc = [&](size_t bytes) -> char* {
    char* p = ws + off;
    off += (bytes + 255) & ~(size_t)255;
    return p;
  };
  bf16*  xc    = (bf16*)alloc((size_t)TT * BB * DD * 2 * 2);
  bf16*  w0c   = (bf16*)alloc((size_t)NG4 * DD * 2 * 2);
  bf16*  w1c   = (bf16*)alloc((size_t)NG4 * HH * 2 * 2);
  bf16*  wpk0h = (bf16*)alloc((size_t)NG4 * HH * 2);
  bf16*  wpk0l = (bf16*)alloc((size_t)NG4 * HH * 2);
  bf16*  wpk1h = (bf16*)alloc((size_t)NG4 * HH * 2);
  bf16*  wpk1l = (bf16*)alloc((size_t)NG4 * HH * 2);
  bf16*  svc0  = (bf16*)alloc((size_t)(ct + 1) * SLOTB);  // layer-0 h chain
  bf16*  svc1  = (bf16*)alloc((size_t)(ct + 1) * SLOTB);  // layer-1 h chain
  float* xgT0  = (float*)alloc((size_t)ct * BB * NG4 * 4);
  float* xgT1  = (float*)alloc((size_t)ct * BB * NG4 * 4);
  float* c0    = (float*)alloc((size_t)BB * HH * 4);
  float* c1    = (float*)alloc((size_t)BB * HH * 4);
  int*   flagsA = (int*)alloc((size_t)NWG * FSTRIDE * 4);
  int*   flagsB = (int*)alloc((size_t)NWG * FSTRIDE * 4);

  cast_interleave<<<(TT * BB * DD / 8 + 255) / 256, 256, 0, stream>>>(x, xc, TT * BB * DD / 8);
  cast_interleave<<<(NG4 * DD / 8 + 255) / 256, 256, 0, stream>>>(wih0, w0c, NG4 * DD / 8);
  cast_interleave<<<(NG4 * HH / 8 + 255) / 256, 256, 0, stream>>>(wih1, w1c, NG4 * HH / 8);
  pack_whh_frag<<<2048, 256, 0, stream>>>(whh0, wpk0h, wpk0l);
  pack_whh_frag<<<2048, 256, 0, stream>>>(whh1, wpk1h, wpk1l);

  hipMemsetAsync(svc0, 0, SLOTB, stream);             // h0 initial state (slot 0)
  hipMemsetAsync(svc1, 0, SLOTB, stream);             // h1 initial state (slot 0)
  hipMemsetAsync(c0, 0, (size_t)BB * HH * 4, stream);
  hipMemsetAsync(c1, 0, (size_t)BB * HH * 4, stream);
  hipMemsetAsync(flagsA, 0, (size_t)NWG * FSTRIDE * 4, stream); // once; monotonic
  hipMemsetAsync(flagsB, 0, (size_t)NWG * FSTRIDE * 4, stream);

  const int gemmGrid = (ct * BB / BM) * (NG4 / BN);   // 1024 at ct=64
  int fb0 = 0, fb1 = 0;

  ScanArgs a0 = {wpk0h, wpk0l, xgT0, svc0, c0, flagsB, (float*)nullptr, 0};  // layer-0
  ScanArgs a1 = {wpk1h, wpk1l, xgT1, svc1, c1, flagsA, (float*)nullptr, 0};  // layer-1

  // prologue: layer-0 projection chunk 0 + solo scan
  GemmArgs g0c0 = {xc, w0c, bih0, bhh0, xgT0, DD, 0};
  gemm_dual<<<gemmGrid, 256, 0, stream>>>(g0c0, g0c0, gemmGrid);
  a0.fbase = fb0;
  lstm_scan<<<NWG, 512, 0, stream>>>(a0, a0, NWG, ct);
  fb0 += ct;

  for (int c = 0; c < nch; ++c) {
    GemmArgs g1 = {svc0 + SLOT, w1c, bih1, bhh1, xgT1, HH, 1};   // layer-1 proj c
    a1.outp = out + (size_t)c * ct * BB * HH;
    if (c + 1 < nch) {
      GemmArgs g0n = {xc + (size_t)(c + 1) * ct * BB * DD * 2,
                      w0c, bih0, bhh0, xgT0, DD, 0};             // layer-0 proj c+1
      gemm_dual<<<2 * gemmGrid, 256, 0, stream>>>(g1, g0n, gemmGrid);
      a1.fbase = fb1;
      a0.fbase = fb0;
      // fused: WGs 0..127 = layer-1 chunk c ; WGs 128..255 = layer-0 chunk c+1
      lstm_scan<<<2 * NWG, 512, 0, stream>>>(a1, a0, NWG, ct);
      fb1 += ct; fb0 += ct;
    } else {
      gemm_dual<<<gemmGrid, 256, 0, stream>>>(g1, g1, gemmGrid);
      a1.fbase = fb1;
      lstm_scan<<<NWG, 512, 0, stream>>>(a1, a1, NWG, ct);
      fb1 += ct;
    }
  }
}